// Round 12
// baseline (194.462 us; speedup 1.0000x reference)
//
#include <hip/hip_runtime.h>
#include <hip/hip_bf16.h>

typedef __bf16 bf16x8 __attribute__((ext_vector_type(8)));
typedef float f32x4 __attribute__((ext_vector_type(4)));
typedef unsigned short u16x4 __attribute__((ext_vector_type(4)));
typedef unsigned short u16x8 __attribute__((ext_vector_type(8)));
typedef unsigned uint4v __attribute__((ext_vector_type(4)));

#define B_ 4
#define S_ 2048
#define D_ 1024
#define H_ 16
#define HD_ 64

__device__ __forceinline__ unsigned short f2bf(float f) {
  unsigned u = __float_as_uint(f);
  u += 0x7fff + ((u >> 16) & 1);   // round-to-nearest-even
  return (unsigned short)(u >> 16);
}

__device__ __forceinline__ void gload16(const void* g, void* l) {
  __builtin_amdgcn_global_load_lds((const __attribute__((address_space(1))) unsigned int*)g,
                                   (__attribute__((address_space(3))) unsigned int*)l,
                                   16, 0, 0);
}

// ---------------- pack kernels ----------------
__global__ void pack_x_k(const float* __restrict__ in, unsigned short* __restrict__ out, int n4) {
  int i = blockIdx.x * blockDim.x + threadIdx.x;
  int stride = gridDim.x * blockDim.x;
  for (; i < n4; i += stride) {
    float4 v = reinterpret_cast<const float4*>(in)[i];
    u16x4 o = {f2bf(v.x), f2bf(v.y), f2bf(v.z), f2bf(v.w)};
    reinterpret_cast<u16x4*>(out)[i] = o;
  }
}

// Wq/Wk/Wv [H][D][HD] f32 -> Wt [3*D][D] bf16, Wt[h*64+e (+1024/2048)][d] = W[h][d][e]
__global__ void pack_wqkv_k(const float* __restrict__ Wq, const float* __restrict__ Wk,
                            const float* __restrict__ Wv, unsigned short* __restrict__ Wt) {
  int o = blockIdx.x * blockDim.x + threadIdx.x;  // 0 .. 3*1024*1024-1
  int n = o >> 10;
  int d = o & 1023;
  const float* W = (n < 1024) ? Wq : (n < 2048) ? Wk : Wv;
  int nn = n & 1023;
  int h = nn >> 6, e = nn & 63;
  Wt[o] = f2bf(W[(h << 16) + (d << 6) + e]);
}

// ---------------- 256x128 2-phase GEMM: C[M][N] = A[M][K] * Bt[N][K]^T, bf16 out ----
// 512 threads = 8 waves (2M x 4N): per-wave output 128x32 (interleaved 16-blocks:
// row-blocks 2i+wm, col-blocks 4j+wn). BK=64. LDS 96 KiB = 2buf x {A0,A1,B} x 128x64.
// Grid 32x24 = 768 blocks = exactly 3 even dispatch rounds on 256 CUs (tail fix).
// T2 chunk swizzle pos = cc ^ (row&7), via linear gload_lds dest + pre-swizzled src.
// Phases per K-tile t: ph0 {read A0-frags+B-frags; stage A0,B(t+1); barrier; 16 MFMA;
// vmcnt(4); barrier}  ph1 {read A1-frags; stage A1(t+1); barrier; 16 MFMA; vmcnt(2);
// barrier}. FIFO-derived counted waits, never 0 mid-loop.
__global__ __launch_bounds__(512, 2) void gemm256_k(const unsigned short* __restrict__ A,
                                                    const unsigned short* __restrict__ Bt,
                                                    unsigned short* __restrict__ C,
                                                    int M, int N, int K) {
  __shared__ __align__(16) unsigned short lds[2][3][128 * 64];  // [buf][A0,A1,B]
  const int tid = threadIdx.x;
  const int wid = tid >> 6, lane = tid & 63;
  const int r = lane & 15, g = lane >> 4;
  const int wm = wid >> 2, wn = wid & 3;

  // XCD-locality map (grid 32x24 = 768 = 8 XCD x 96): per-XCD 8 arows x 12 bcols
  const int i_hw = blockIdx.y * gridDim.x + blockIdx.x;
  const int xcd = i_hw & 7, j = i_hw >> 3;          // j in 0..95
  const long arow0 = (long)((xcd & 3) * 8 + (j & 7)) * 256;
  const long bcol0 = (long)((xcd >> 2) * 12 + (j >> 3)) * 128;

  const f32x4 z4 = {0.f, 0.f, 0.f, 0.f};
  f32x4 acc[8][2];
#pragma unroll
  for (int m = 0; m < 8; ++m)
#pragma unroll
    for (int n = 0; n < 2; ++n) acc[m][n] = z4;

  // stage one 128x64 half: which = 0 (A rows 0..127), 1 (A rows 128..255), 2 (B)
  auto stage_half = [&](int kt, int which) {
    const unsigned short* src = (which == 2) ? Bt + bcol0 * K : A + (arow0 + 128 * which) * K;
    const int k0 = kt << 6;
    unsigned short* base = &lds[kt & 1][which][0];
#pragma unroll
    for (int c = 0; c < 2; ++c) {
      const int jj = c * 512 + tid;                // 16B chunk id 0..1023
      const int row = jj >> 3, cc = jj & 7;
      const int ccs = cc ^ (row & 7);              // pre-swizzled global source chunk
      gload16(src + (long)row * K + k0 + ccs * 8, base + jj * 8);
    }
  };

  bf16x8 af[4][2], bv[2][2];
  auto read_a = [&](int buf, int mh) {             // 8 x ds_read_b128
#pragma unroll
    for (int i2 = 0; i2 < 4; ++i2)
#pragma unroll
      for (int kk = 0; kk < 2; ++kk) {
        const int rowh = (2 * i2 + wm) * 16 + r;   // row within the 128-half
        af[i2][kk] = *(const bf16x8*)&lds[buf][mh][rowh * 64 + (((kk << 2) + g) ^ (rowh & 7)) * 8];
      }
  };
  auto read_b = [&](int buf) {                     // 4 x ds_read_b128
#pragma unroll
    for (int j2 = 0; j2 < 2; ++j2)
#pragma unroll
      for (int kk = 0; kk < 2; ++kk) {
        const int rowh = (4 * j2 + wn) * 16 + r;
        bv[j2][kk] = *(const bf16x8*)&lds[buf][2][rowh * 64 + (((kk << 2) + g) ^ (rowh & 7)) * 8];
      }
  };
  auto mma_h = [&](int mh) {                       // 16 MFMA for one A-half
    __builtin_amdgcn_s_setprio(1);
#pragma unroll
    for (int kk = 0; kk < 2; ++kk)
#pragma unroll
      for (int i2 = 0; i2 < 4; ++i2)
#pragma unroll
        for (int j2 = 0; j2 < 2; ++j2)
          acc[4 * mh + i2][j2] = __builtin_amdgcn_mfma_f32_16x16x32_bf16(
              af[i2][kk], bv[j2][kk], acc[4 * mh + i2][j2], 0, 0, 0);
    __builtin_amdgcn_s_setprio(0);
  };

  const int nk = K >> 6;
  // prologue: A0(0), B(0), A1(0)
  stage_half(0, 0);
  stage_half(0, 2);
  stage_half(0, 1);
  asm volatile("s_waitcnt vmcnt(2)" ::: "memory");  // A0(0),B(0) landed
  asm volatile("s_barrier" ::: "memory");

  for (int t = 0; t < nk; ++t) {
    const int buf = t & 1;
    const bool pre = (t + 1 < nk);
    // ---- phase 0: A-half 0
    read_a(buf, 0);
    read_b(buf);
    if (pre) { stage_half(t + 1, 0); stage_half(t + 1, 2); }
    asm volatile("s_barrier" ::: "memory");
    mma_h(0);
    if (pre) asm volatile("s_waitcnt vmcnt(4)" ::: "memory");   // A1(t) landed
    else     asm volatile("s_waitcnt vmcnt(0)" ::: "memory");
    asm volatile("s_waitcnt lgkmcnt(0)\n\ts_barrier" ::: "memory");
    // ---- phase 1: A-half 1
    read_a(buf, 1);
    if (pre) stage_half(t + 1, 1);
    asm volatile("s_barrier" ::: "memory");
    mma_h(1);
    if (pre) asm volatile("s_waitcnt vmcnt(2)" ::: "memory");   // A0(t+1),B(t+1) landed
    asm volatile("s_waitcnt lgkmcnt(0)\n\ts_barrier" ::: "memory");
  }

#pragma unroll
  for (int m = 0; m < 8; ++m)
#pragma unroll
    for (int n = 0; n < 2; ++n)
#pragma unroll
      for (int rr = 0; rr < 4; ++rr) {
        const long row = arow0 + (2 * m + wm) * 16 + g * 4 + rr;
        const long col = bcol0 + (4 * n + wn) * 16 + r;
        C[row * N + col] = f2bf(acc[m][n][rr]);
      }
}

// ---------------- 128x128 GEMM (out-proj): C = A * Bt^T + bias, f32 out ----------------
__global__ __launch_bounds__(256, 2) void gemm_bt_k(const unsigned short* __restrict__ A,
                                                    const unsigned short* __restrict__ Bt,
                                                    float* __restrict__ C,
                                                    const float* __restrict__ bias,
                                                    int M, int N, int K) {
  __shared__ __align__(16) unsigned short lA[2][128 * 64];
  __shared__ __align__(16) unsigned short lB[2][128 * 64];
  const int tid = threadIdx.x;
  const int wid = tid >> 6, lane = tid & 63;
  const int r = lane & 15, g = lane >> 4;
  const long arow0 = (long)blockIdx.x * 128;
  const long brow0 = (long)blockIdx.y * 128;
  const int wr = (wid >> 1) * 64, wc = (wid & 1) * 64;

  const f32x4 z4 = {0.f, 0.f, 0.f, 0.f};
  f32x4 acc[4][4];
#pragma unroll
  for (int m = 0; m < 4; ++m)
#pragma unroll
    for (int n = 0; n < 4; ++n) acc[m][n] = z4;

  auto stage = [&](int buf, int k0) {
#pragma unroll
    for (int c = 0; c < 4; ++c) {
      const int j = c * 256 + wid * 64 + lane;
      const int row = j >> 3, col = (j & 7) * 8;
      gload16(A + (arow0 + row) * K + k0 + col, &lA[buf][(c * 256 + wid * 64) * 8]);
      gload16(Bt + (brow0 + row) * K + k0 + col, &lB[buf][(c * 256 + wid * 64) * 8]);
    }
  };

  stage(0, 0);
  __syncthreads();
  const int nk = K >> 6;
  for (int kt = 0; kt < nk; ++kt) {
    const int cur = kt & 1;
    if (kt + 1 < nk) stage(cur ^ 1, (kt + 1) << 6);
#pragma unroll
    for (int kk = 0; kk < 2; ++kk) {
      bf16x8 af[4], bfr[4];
#pragma unroll
      for (int m = 0; m < 4; ++m)
        af[m] = *(const bf16x8*)&lA[cur][(wr + m * 16 + r) * 64 + kk * 32 + g * 8];
#pragma unroll
      for (int n = 0; n < 4; ++n)
        bfr[n] = *(const bf16x8*)&lB[cur][(wc + n * 16 + r) * 64 + kk * 32 + g * 8];
#pragma unroll
      for (int m = 0; m < 4; ++m)
#pragma unroll
        for (int n = 0; n < 4; ++n)
          acc[m][n] = __builtin_amdgcn_mfma_f32_16x16x32_bf16(af[m], bfr[n], acc[m][n], 0, 0, 0);
    }
    __syncthreads();
  }

#pragma unroll
  for (int m = 0; m < 4; ++m) {
#pragma unroll
    for (int n = 0; n < 4; ++n) {
#pragma unroll
      for (int rr = 0; rr < 4; ++rr) {
        const long row = arow0 + wr + m * 16 + g * 4 + rr;
        const long col = brow0 + wc + n * 16 + r;
        C[row * N + col] = acc[m][n][rr] + bias[col];
      }
    }
  }
}

// ---------------- flash attention (round-11 structure, occupancy 3) ----------------
// qkv: [B*S][3072] bf16. QBLK=128 (2 q-subtiles/wave), KVBLK=64.
// Swapped QK^T: st = mfma(K,Q) -> lane holds 16 raw kv scores for q = lane&15.
// Softmax in RAW score domain: p = __expf(fma(s, 0.125, -m*0.125)).
// P repacked in-register via cvt_pk + permlane; PV = mfma(pf, vf); corr/l via shfl.
__global__ __launch_bounds__(256, 3) void attn_k(const unsigned short* __restrict__ qkv,
                                                 unsigned short* __restrict__ out) {
  __shared__ __align__(16) unsigned short lK[2][64 * 64];
  __shared__ __align__(16) unsigned short lVt[2][64 * 64];

  const int tid = threadIdx.x, wid = tid >> 6, lane = tid & 63;
  const int r = lane & 15, g = lane >> 4;
  const int bh = blockIdx.x;
  const int b = bh >> 4, h = bh & 15;
  const int qb = 15 - (int)blockIdx.y;   // long blocks dispatch first
  const int q0 = qb * 128;

  const long base = ((long)b * S_) * 3072 + h * 64;
  const unsigned short* Qg = qkv + base;
  const unsigned short* Kg = qkv + base + 1024;
  const unsigned short* Vg = qkv + base + 2048;

  // Q fragments for both subtiles
  int qrow[2];
  bf16x8 qf[2][2];
#pragma unroll
  for (int qs = 0; qs < 2; ++qs) {
    qrow[qs] = q0 + qs * 64 + wid * 16 + r;
#pragma unroll
    for (int kk = 0; kk < 2; ++kk)
      qf[qs][kk] = *(const bf16x8*)&Qg[(long)qrow[qs] * 3072 + kk * 32 + g * 8];
  }

  const f32x4 z4 = {0.f, 0.f, 0.f, 0.f};
  f32x4 o[2][4];
#pragma unroll
  for (int qs = 0; qs < 2; ++qs)
#pragma unroll
    for (int nt = 0; nt < 4; ++nt) o[qs][nt] = z4;
  float m_i[2] = {-1e30f, -1e30f};
  float l_i[2] = {0.f, 0.f};

  // double-buffer staging registers
  u16x8 kreg[2], vreg[2];
  auto load_regs = [&](int t0) {
#pragma unroll
    for (int c = 0; c < 2; ++c) {
      const int j = c * 256 + tid;
      const int tt = j >> 3, e0 = (j & 7) * 8;   // K: row tt, chunk e0/8
      kreg[c] = *(const u16x8*)&Kg[(long)(t0 + tt) * 3072 + e0];
      const int tc = j & 63, ec = j >> 6;        // V: token tc, elems ec*8..
      vreg[c] = *(const u16x8*)&Vg[(long)(t0 + tc) * 3072 + ec * 8];
    }
  };
  auto write_lds = [&](int buf) {
#pragma unroll
    for (int c = 0; c < 2; ++c) {
      const int j = c * 256 + tid;
      const int row = j >> 3, cc = j & 7;
      *(u16x8*)&lK[buf][(row * 8 + (cc ^ (row & 7))) * 8] = kreg[c];
      const int tc = j & 63, ec = j >> 6;
#pragma unroll
      for (int i = 0; i < 8; ++i) {
        const int e = ec * 8 + i;                 // lVt row = feature e, col = token tc
        lVt[buf][e * 64 + (tc ^ (i * 8))] = vreg[c][i];
      }
    }
  };

  const int ntiles = (q0 >> 6) + 2;  // kv tiles 0 .. q0/64+1
  load_regs(0);
  write_lds(0);

  for (int t = 0; t < ntiles; ++t) {
    const int cur = t & 1;
    if (t + 1 < ntiles) load_regs((t + 1) << 6);  // issue early: latency hides under compute
    __syncthreads();                              // LDS[cur] ready; prior reads of cur^1 done

    const int t0 = t << 6;
    const bool act0 = (t < ntiles - 1);   // qs=0 rows all < q0+64
    const bool diag0 = (t == ntiles - 2); // t0 == q0
    const bool diag1 = (t == ntiles - 1); // t0 == q0+64

    // S^T = K Q^T (swapped operands): st[qs][tt][rg] = S_raw[qrow[qs]][t0+16tt+4g+rg]
    f32x4 st[2][4];
#pragma unroll
    for (int tt = 0; tt < 4; ++tt) { st[0][tt] = z4; st[1][tt] = z4; }
    __builtin_amdgcn_s_setprio(1);
#pragma unroll
    for (int kk = 0; kk < 2; ++kk)
#pragma unroll
      for (int tt = 0; tt < 4; ++tt) {
        const int row = tt * 16 + r, cc = kk * 4 + g;
        bf16x8 kf = *(const bf16x8*)&lK[cur][(row * 8 + (cc ^ (row & 7))) * 8];
        st[1][tt] = __builtin_amdgcn_mfma_f32_16x16x32_bf16(kf, qf[1][kk], st[1][tt], 0, 0, 0);
        if (act0)
          st[0][tt] = __builtin_amdgcn_mfma_f32_16x16x32_bf16(kf, qf[0][kk], st[0][tt], 0, 0, 0);
      }
    __builtin_amdgcn_s_setprio(0);

    // per-lane softmax + in-register P repack, per active subtile
    bf16x8 pf[2][2];
    unsigned corr_bits[2] = {0x3f800000u, 0x3f800000u};
    bool dodef[2] = {true, true};
#pragma unroll
    for (int qs = 0; qs < 2; ++qs) {
      if (qs == 0 && !act0) continue;
      const bool diag = qs ? diag1 : diag0;
      float sv[16];
#pragma unroll
      for (int tt = 0; tt < 4; ++tt)
#pragma unroll
        for (int rg = 0; rg < 4; ++rg) {
          float s = st[qs][tt][rg];  // raw score (scale folded into exp)
          if (diag && (t0 + tt * 16 + g * 4 + rg > qrow[qs])) s = -1e30f;
          sv[tt * 4 + rg] = s;
        }
      float h0 = fmaxf(fmaxf(fmaxf(sv[0], sv[1]), fmaxf(sv[2], sv[3])),
                       fmaxf(fmaxf(sv[4], sv[5]), fmaxf(sv[6], sv[7])));
      float h1 = fmaxf(fmaxf(fmaxf(sv[8], sv[9]), fmaxf(sv[10], sv[11])),
                       fmaxf(fmaxf(sv[12], sv[13]), fmaxf(sv[14], sv[15])));
      const float pmax = fmaxf(h0, h1);
      const bool defer = __all(pmax - m_i[qs] <= 64.f);  // T13: 64 raw == 8 scaled
      float corr = 1.f;
      if (!defer) {
        float mx = fmaxf(pmax, m_i[qs]);
        mx = fmaxf(mx, __shfl_xor(mx, 16, 64));
        mx = fmaxf(mx, __shfl_xor(mx, 32, 64));
        corr = __expf((m_i[qs] - mx) * 0.125f);
        m_i[qs] = mx;
      }
      dodef[qs] = defer;
      corr_bits[qs] = __float_as_uint(corr);
      const float m8 = m_i[qs] * 0.125f;
      float p[16];
      float rs = 0.f;
#pragma unroll
      for (int i = 0; i < 16; ++i) {
        p[i] = __expf(__builtin_fmaf(sv[i], 0.125f, -m8));
        rs += p[i];
      }
      rs += __shfl_xor(rs, 16, 64);
      rs += __shfl_xor(rs, 32, 64);
      l_i[qs] = l_i[qs] * corr + rs;
      // pack pairs: c[tt][e] covers kv pair (16tt + 4g + 2e)
      unsigned cw[4][2];
#pragma unroll
      for (int tt = 0; tt < 4; ++tt)
#pragma unroll
        for (int e = 0; e < 2; ++e)
          asm("v_cvt_pk_bf16_f32 %0, %1, %2"
              : "=v"(cw[tt][e]) : "v"(p[tt * 4 + 2 * e]), "v"(p[tt * 4 + 2 * e + 1]));
      // redistribute to A-frag words
#pragma unroll
      for (int kk = 0; kk < 2; ++kk) {
        unsigned x0 = cw[2 * kk][0], y0 = cw[2 * kk + 1][0];
        unsigned x1 = cw[2 * kk][1], y1 = cw[2 * kk + 1][1];
        asm volatile("v_permlane32_swap_b32 %0, %1" : "+v"(x0), "+v"(y0));
        asm volatile("v_permlane16_swap_b32 %0, %1" : "+v"(x0), "+v"(y0));
        asm volatile("v_permlane32_swap_b32 %0, %1" : "+v"(x1), "+v"(y1));
        asm volatile("v_permlane16_swap_b32 %0, %1" : "+v"(x1), "+v"(y1));
        uint4v w = {x0, x1, y0, y1};  // kv pairs (8g+0),(8g+2),(8g+4),(8g+6)
        pf[qs][kk] = *(bf16x8*)&w;
      }
    }
    // O rescale (rows live at lanes r'=4g+rr; corr per-lane at r) — only when needed
#pragma unroll
    for (int qs = 0; qs < 2; ++qs) {
      if (qs == 0 && !act0) continue;
      if (!dodef[qs]) {
        const float corr = __uint_as_float(corr_bits[qs]);
#pragma unroll
        for (int rr = 0; rr < 4; ++rr) {
          const float c = __shfl(corr, g * 4 + rr, 64);
#pragma unroll
          for (int nt = 0; nt < 4; ++nt) o[qs][nt][rr] *= c;
        }
      }
    }

    // O += P V
    __builtin_amdgcn_s_setprio(1);
#pragma unroll
    for (int kk = 0; kk < 2; ++kk)
#pragma unroll
      for (int nt = 0; nt < 4; ++nt) {
        const int row = nt * 16 + r, cc = kk * 4 + g;
        const bf16x8 vf = *(const bf16x8*)&lVt[cur][(row * 8 + (cc ^ (row & 7))) * 8];
        o[1][nt] = __builtin_amdgcn_mfma_f32_16x16x32_bf16(pf[1][kk], vf, o[1][nt], 0, 0, 0);
        if (act0)
          o[0][nt] = __builtin_amdgcn_mfma_f32_16x16x32_bf16(pf[0][kk], vf, o[0][nt], 0, 0, 0);
      }
    __builtin_amdgcn_s_setprio(0);

    if (t + 1 < ntiles) write_lds(cur ^ 1);  // safe: all waves passed this tile's barrier
  }

#pragma unroll
  for (int qs = 0; qs < 2; ++qs) {
    float linv[4];
#pragma unroll
    for (int rr = 0; rr < 4; ++rr)
      linv[rr] = 1.f / __shfl(l_i[qs], g * 4 + rr, 64);
#pragma unroll
    for (int nt = 0; nt < 4; ++nt)
#pragma unroll
      for (int rr = 0; rr < 4; ++rr) {
        const long s = q0 + qs * 64 + wid * 16 + g * 4 + rr;
        out[((long)b * S_ + s) * 1024 + h * 64 + nt * 16 + r] = f2bf(o[qs][nt][rr] * linv[rr]);
      }
  }
}

extern "C" void kernel_launch(void* const* d_in, const int* in_sizes, int n_in,
                              void* d_out, int out_size, void* d_ws, size_t ws_size,
                              hipStream_t stream) {
  const float* x = (const float*)d_in[0];
  const float* Wq = (const float*)d_in[1];
  const float* Wk = (const float*)d_in[2];
  const float* Wv = (const float*)d_in[3];
  const float* Wo = (const float*)d_in[4];
  const float* bo = (const float*)d_in[5];
  float* out = (float*)d_out;

  char* ws = (char*)d_ws;
  unsigned short* Xb = (unsigned short*)(ws);                        // 16 MiB: x bf16 [8192][1024]
  unsigned short* Wt = (unsigned short*)(ws + (16ul << 20));         //  6 MiB: qkv weight B^T [3072][1024]
  unsigned short* Wob = (unsigned short*)(ws + (22ul << 20));        //  2 MiB: Wo bf16 [1024][1024]
  unsigned short* QKV = (unsigned short*)(ws + (24ul << 20));        // 48 MiB: [8192][3072]
  unsigned short* AO = (unsigned short*)(ws + (72ul << 20));         // 16 MiB: attn out [8192][1024]

  pack_x_k<<<2048, 256, 0, stream>>>(x, Xb, (B_ * S_ * D_) / 4);
  pack_x_k<<<512, 256, 0, stream>>>(Wo, Wob, (D_ * D_) / 4);
  pack_wqkv_k<<<(3 * D_ * D_) / 256, 256, 0, stream>>>(Wq, Wk, Wv, Wt);

  gemm256_k<<<dim3(32, 24), 512, 0, stream>>>(Xb, Wt, QKV, B_ * S_, 3 * D_, D_);
  attn_k<<<dim3(64, 16), 256, 0, stream>>>(QKV, AO);
  gemm_bt_k<<<dim3(64, 8), 256, 0, stream>>>(AO, Wob, out, bo, B_ * S_, D_, D_);
}

// Round 13
// 192.126 us; speedup vs baseline: 1.0122x; 1.0122x over previous
//
#include <hip/hip_runtime.h>
#include <hip/hip_bf16.h>

typedef __bf16 bf16x8 __attribute__((ext_vector_type(8)));
typedef float f32x4 __attribute__((ext_vector_type(4)));
typedef unsigned short u16x4 __attribute__((ext_vector_type(4)));
typedef unsigned short u16x8 __attribute__((ext_vector_type(8)));
typedef unsigned uint4v __attribute__((ext_vector_type(4)));

#define B_ 4
#define S_ 2048
#define D_ 1024
#define H_ 16
#define HD_ 64

__device__ __forceinline__ unsigned short f2bf(float f) {
  unsigned u = __float_as_uint(f);
  u += 0x7fff + ((u >> 16) & 1);   // round-to-nearest-even
  return (unsigned short)(u >> 16);
}

__device__ __forceinline__ void gload16(const void* g, void* l) {
  __builtin_amdgcn_global_load_lds((const __attribute__((address_space(1))) unsigned int*)g,
                                   (__attribute__((address_space(3))) unsigned int*)l,
                                   16, 0, 0);
}

// ---------------- pack kernels ----------------
__global__ void pack_x_k(const float* __restrict__ in, unsigned short* __restrict__ out, int n4) {
  int i = blockIdx.x * blockDim.x + threadIdx.x;
  int stride = gridDim.x * blockDim.x;
  for (; i < n4; i += stride) {
    float4 v = reinterpret_cast<const float4*>(in)[i];
    u16x4 o = {f2bf(v.x), f2bf(v.y), f2bf(v.z), f2bf(v.w)};
    reinterpret_cast<u16x4*>(out)[i] = o;
  }
}

// Wq/Wk/Wv [H][D][HD] f32 -> Wt [3*D][D] bf16, Wt[h*64+e (+1024/2048)][d] = W[h][d][e]
__global__ void pack_wqkv_k(const float* __restrict__ Wq, const float* __restrict__ Wk,
                            const float* __restrict__ Wv, unsigned short* __restrict__ Wt) {
  int o = blockIdx.x * blockDim.x + threadIdx.x;  // 0 .. 3*1024*1024-1
  int n = o >> 10;
  int d = o & 1023;
  const float* W = (n < 1024) ? Wq : (n < 2048) ? Wk : Wv;
  int nn = n & 1023;
  int h = nn >> 6, e = nn & 63;
  Wt[o] = f2bf(W[(h << 16) + (d << 6) + e]);
}

// ---------------- 256x128 2-phase GEMM (QKV proj) ----------------
// C layout split: cols [0,2048) -> QK[row][col] (Q|K per head); cols [2048,3072)
// -> VT[((b*16+h)*64+e)][s] (V transposed per head, u16x4 stores). Branch is
// block-uniform (bcol0 is 128-aligned).
__global__ __launch_bounds__(512, 2) void gemm256_k(const unsigned short* __restrict__ A,
                                                    const unsigned short* __restrict__ Bt,
                                                    unsigned short* __restrict__ QK,
                                                    unsigned short* __restrict__ VT,
                                                    int M, int N, int K) {
  __shared__ __align__(16) unsigned short lds[2][3][128 * 64];  // [buf][A0,A1,B]
  const int tid = threadIdx.x;
  const int wid = tid >> 6, lane = tid & 63;
  const int r = lane & 15, g = lane >> 4;
  const int wm = wid >> 2, wn = wid & 3;

  // XCD-locality map (grid 32x24 = 768 = 8 XCD x 96): per-XCD 8 arows x 12 bcols
  const int i_hw = blockIdx.y * gridDim.x + blockIdx.x;
  const int xcd = i_hw & 7, j = i_hw >> 3;          // j in 0..95
  const long arow0 = (long)((xcd & 3) * 8 + (j & 7)) * 256;
  const long bcol0 = (long)((xcd >> 2) * 12 + (j >> 3)) * 128;

  const f32x4 z4 = {0.f, 0.f, 0.f, 0.f};
  f32x4 acc[8][2];
#pragma unroll
  for (int m = 0; m < 8; ++m)
#pragma unroll
    for (int n = 0; n < 2; ++n) acc[m][n] = z4;

  // stage one 128x64 half: which = 0 (A rows 0..127), 1 (A rows 128..255), 2 (B)
  auto stage_half = [&](int kt, int which) {
    const unsigned short* src = (which == 2) ? Bt + bcol0 * K : A + (arow0 + 128 * which) * K;
    const int k0 = kt << 6;
    unsigned short* base = &lds[kt & 1][which][0];
#pragma unroll
    for (int c = 0; c < 2; ++c) {
      const int jj = c * 512 + tid;                // 16B chunk id 0..1023
      const int row = jj >> 3, cc = jj & 7;
      const int ccs = cc ^ (row & 7);              // pre-swizzled global source chunk
      gload16(src + (long)row * K + k0 + ccs * 8, base + jj * 8);
    }
  };

  bf16x8 af[4][2], bv[2][2];
  auto read_a = [&](int buf, int mh) {             // 8 x ds_read_b128
#pragma unroll
    for (int i2 = 0; i2 < 4; ++i2)
#pragma unroll
      for (int kk = 0; kk < 2; ++kk) {
        const int rowh = (2 * i2 + wm) * 16 + r;   // row within the 128-half
        af[i2][kk] = *(const bf16x8*)&lds[buf][mh][rowh * 64 + (((kk << 2) + g) ^ (rowh & 7)) * 8];
      }
  };
  auto read_b = [&](int buf) {                     // 4 x ds_read_b128
#pragma unroll
    for (int j2 = 0; j2 < 2; ++j2)
#pragma unroll
      for (int kk = 0; kk < 2; ++kk) {
        const int rowh = (4 * j2 + wn) * 16 + r;
        bv[j2][kk] = *(const bf16x8*)&lds[buf][2][rowh * 64 + (((kk << 2) + g) ^ (rowh & 7)) * 8];
      }
  };
  auto mma_h = [&](int mh) {                       // 16 MFMA for one A-half
    __builtin_amdgcn_s_setprio(1);
#pragma unroll
    for (int kk = 0; kk < 2; ++kk)
#pragma unroll
      for (int i2 = 0; i2 < 4; ++i2)
#pragma unroll
        for (int j2 = 0; j2 < 2; ++j2)
          acc[4 * mh + i2][j2] = __builtin_amdgcn_mfma_f32_16x16x32_bf16(
              af[i2][kk], bv[j2][kk], acc[4 * mh + i2][j2], 0, 0, 0);
    __builtin_amdgcn_s_setprio(0);
  };

  const int nk = K >> 6;
  // prologue: A0(0), B(0), A1(0)
  stage_half(0, 0);
  stage_half(0, 2);
  stage_half(0, 1);
  asm volatile("s_waitcnt vmcnt(2)" ::: "memory");  // A0(0),B(0) landed
  asm volatile("s_barrier" ::: "memory");

  for (int t = 0; t < nk; ++t) {
    const int buf = t & 1;
    const bool pre = (t + 1 < nk);
    // ---- phase 0: A-half 0
    read_a(buf, 0);
    read_b(buf);
    if (pre) { stage_half(t + 1, 0); stage_half(t + 1, 2); }
    asm volatile("s_barrier" ::: "memory");
    mma_h(0);
    if (pre) asm volatile("s_waitcnt vmcnt(4)" ::: "memory");   // A1(t) landed
    else     asm volatile("s_waitcnt vmcnt(0)" ::: "memory");
    asm volatile("s_waitcnt lgkmcnt(0)\n\ts_barrier" ::: "memory");
    // ---- phase 1: A-half 1
    read_a(buf, 1);
    if (pre) stage_half(t + 1, 1);
    asm volatile("s_barrier" ::: "memory");
    mma_h(1);
    if (pre) asm volatile("s_waitcnt vmcnt(2)" ::: "memory");   // A0(t+1),B(t+1) landed
    asm volatile("s_waitcnt lgkmcnt(0)\n\ts_barrier" ::: "memory");
  }

  if (bcol0 < 2048) {
    // Q|K columns: row-major [8192][2048]
#pragma unroll
    for (int m = 0; m < 8; ++m)
#pragma unroll
      for (int n = 0; n < 2; ++n)
#pragma unroll
        for (int rr = 0; rr < 4; ++rr) {
          const long row = arow0 + (2 * m + wm) * 16 + g * 4 + rr;
          const long col = bcol0 + (4 * n + wn) * 16 + r;
          QK[row * 2048 + col] = f2bf(acc[m][n][rr]);
        }
  } else {
    // V columns: write transposed VT[((b*16+h)*64+e)][s], 4 consecutive tokens/lane
#pragma unroll
    for (int m = 0; m < 8; ++m) {
      const long row0 = arow0 + (2 * m + wm) * 16 + g * 4;  // 4 consecutive rows
      const long b = row0 >> 11, s = row0 & 2047;           // no b-crossing (256|2048)
#pragma unroll
      for (int n = 0; n < 2; ++n) {
        const long vcol = bcol0 - 2048 + (4 * n + wn) * 16 + r;
        const long h = vcol >> 6, e = vcol & 63;
        u16x4 w4;
#pragma unroll
        for (int rr = 0; rr < 4; ++rr) w4[rr] = f2bf(acc[m][n][rr]);
        *(u16x4*)&VT[(((b << 4) + h) * 64 + e) * 2048 + s] = w4;
      }
    }
  }
}

// ---------------- 128x128 GEMM (out-proj): C = A * Bt^T + bias, f32 out ----------------
__global__ __launch_bounds__(256, 2) void gemm_bt_k(const unsigned short* __restrict__ A,
                                                    const unsigned short* __restrict__ Bt,
                                                    float* __restrict__ C,
                                                    const float* __restrict__ bias,
                                                    int M, int N, int K) {
  __shared__ __align__(16) unsigned short lA[2][128 * 64];
  __shared__ __align__(16) unsigned short lB[2][128 * 64];
  const int tid = threadIdx.x;
  const int wid = tid >> 6, lane = tid & 63;
  const int r = lane & 15, g = lane >> 4;
  const long arow0 = (long)blockIdx.x * 128;
  const long brow0 = (long)blockIdx.y * 128;
  const int wr = (wid >> 1) * 64, wc = (wid & 1) * 64;

  const f32x4 z4 = {0.f, 0.f, 0.f, 0.f};
  f32x4 acc[4][4];
#pragma unroll
  for (int m = 0; m < 4; ++m)
#pragma unroll
    for (int n = 0; n < 4; ++n) acc[m][n] = z4;

  auto stage = [&](int buf, int k0) {
#pragma unroll
    for (int c = 0; c < 4; ++c) {
      const int j = c * 256 + wid * 64 + lane;
      const int row = j >> 3, col = (j & 7) * 8;
      gload16(A + (arow0 + row) * K + k0 + col, &lA[buf][(c * 256 + wid * 64) * 8]);
      gload16(Bt + (brow0 + row) * K + k0 + col, &lB[buf][(c * 256 + wid * 64) * 8]);
    }
  };

  stage(0, 0);
  __syncthreads();
  const int nk = K >> 6;
  for (int kt = 0; kt < nk; ++kt) {
    const int cur = kt & 1;
    if (kt + 1 < nk) stage(cur ^ 1, (kt + 1) << 6);
#pragma unroll
    for (int kk = 0; kk < 2; ++kk) {
      bf16x8 af[4], bfr[4];
#pragma unroll
      for (int m = 0; m < 4; ++m)
        af[m] = *(const bf16x8*)&lA[cur][(wr + m * 16 + r) * 64 + kk * 32 + g * 8];
#pragma unroll
      for (int n = 0; n < 4; ++n)
        bfr[n] = *(const bf16x8*)&lB[cur][(wc + n * 16 + r) * 64 + kk * 32 + g * 8];
#pragma unroll
      for (int m = 0; m < 4; ++m)
#pragma unroll
        for (int n = 0; n < 4; ++n)
          acc[m][n] = __builtin_amdgcn_mfma_f32_16x16x32_bf16(af[m], bfr[n], acc[m][n], 0, 0, 0);
    }
    __syncthreads();
  }

#pragma unroll
  for (int m = 0; m < 4; ++m) {
#pragma unroll
    for (int n = 0; n < 4; ++n) {
#pragma unroll
      for (int rr = 0; rr < 4; ++rr) {
        const long row = arow0 + wr + m * 16 + g * 4 + rr;
        const long col = brow0 + wc + n * 16 + r;
        C[row * N + col] = acc[m][n][rr] + bias[col];
      }
    }
  }
}

// ---------------- flash attention ----------------
// qk: [B*S][2048] bf16 (q|k per head); vt: [B][H][64][2048] bf16 (V transposed).
// QBLK=128 (2 q-subtiles/wave), KVBLK=64. Both lK and lVt staged DIRECTLY via
// global_load_lds (pre-swizzled source chunk, linear dest) — no reg staging, no
// scalar transpose scatter. Read side identical to the verified round-11 kernel.
// Swapped QK^T -> per-lane softmax in raw-score domain; cvt_pk+permlane P repack.
__global__ __launch_bounds__(256, 2) void attn_k(const unsigned short* __restrict__ qk,
                                                 const unsigned short* __restrict__ vt,
                                                 unsigned short* __restrict__ out) {
  __shared__ __align__(16) unsigned short lK[2][64 * 64];
  __shared__ __align__(16) unsigned short lVt[2][64 * 64];

  const int tid = threadIdx.x, wid = tid >> 6, lane = tid & 63;
  const int r = lane & 15, g = lane >> 4;
  const int bh = blockIdx.x;
  const int b = bh >> 4, h = bh & 15;
  const int qb = 15 - (int)blockIdx.y;   // long blocks dispatch first
  const int q0 = qb * 128;

  const unsigned short* Qg = qk + ((long)b * S_) * 2048 + h * 64;
  const unsigned short* Kg = Qg + 1024;
  const unsigned short* Vg = vt + ((long)(b * 16 + h)) * 64 * 2048;  // [e][s]

  // Q fragments for both subtiles
  int qrow[2];
  bf16x8 qf[2][2];
#pragma unroll
  for (int qs = 0; qs < 2; ++qs) {
    qrow[qs] = q0 + qs * 64 + wid * 16 + r;
#pragma unroll
    for (int kk = 0; kk < 2; ++kk)
      qf[qs][kk] = *(const bf16x8*)&Qg[(long)qrow[qs] * 2048 + kk * 32 + g * 8];
  }

  const f32x4 z4 = {0.f, 0.f, 0.f, 0.f};
  f32x4 o[2][4];
#pragma unroll
  for (int qs = 0; qs < 2; ++qs)
#pragma unroll
    for (int nt = 0; nt < 4; ++nt) o[qs][nt] = z4;
  float m_i[2] = {-1e30f, -1e30f};
  float l_i[2] = {0.f, 0.f};

  // direct gload16 staging: K row-major, V feature-major; T2 chunk swizzle via
  // pre-swizzled SOURCE chunk (dest linear). Read side unchanged.
  auto stage = [&](int buf, int t0) {
#pragma unroll
    for (int c = 0; c < 2; ++c) {
      const int j = c * 256 + tid;           // chunk id 0..511
      const int row = j >> 3, cc = j & 7;
      const int ccs = (cc ^ (row & 7)) << 3; // source element offset
      gload16(Kg + (long)(t0 + row) * 2048 + ccs, &lK[buf][j * 8]);
      gload16(Vg + (long)row * 2048 + t0 + ccs, &lVt[buf][j * 8]);
    }
  };

  const int ntiles = (q0 >> 6) + 2;  // kv tiles 0 .. q0/64+1
  stage(0, 0);

  for (int t = 0; t < ntiles; ++t) {
    const int cur = t & 1;
    __syncthreads();                              // drains vmcnt: lds[cur] ready;
                                                  // all waves done reading cur^1
    if (t + 1 < ntiles) stage(cur ^ 1, (t + 1) << 6);

    const int t0 = t << 6;
    const bool act0 = (t < ntiles - 1);   // qs=0 rows all < q0+64
    const bool diag0 = (t == ntiles - 2); // t0 == q0
    const bool diag1 = (t == ntiles - 1); // t0 == q0+64

    // S^T = K Q^T (swapped operands): st[qs][tt][rg] = S_raw[qrow[qs]][t0+16tt+4g+rg]
    f32x4 st[2][4];
#pragma unroll
    for (int tt = 0; tt < 4; ++tt) { st[0][tt] = z4; st[1][tt] = z4; }
    __builtin_amdgcn_s_setprio(1);
#pragma unroll
    for (int kk = 0; kk < 2; ++kk)
#pragma unroll
      for (int tt = 0; tt < 4; ++tt) {
        const int row = tt * 16 + r, cc = kk * 4 + g;
        bf16x8 kf = *(const bf16x8*)&lK[cur][(row * 8 + (cc ^ (row & 7))) * 8];
        st[1][tt] = __builtin_amdgcn_mfma_f32_16x16x32_bf16(kf, qf[1][kk], st[1][tt], 0, 0, 0);
        if (act0)
          st[0][tt] = __builtin_amdgcn_mfma_f32_16x16x32_bf16(kf, qf[0][kk], st[0][tt], 0, 0, 0);
      }
    __builtin_amdgcn_s_setprio(0);

    // per-lane softmax + in-register P repack, per active subtile
    bf16x8 pf[2][2];
    unsigned corr_bits[2] = {0x3f800000u, 0x3f800000u};
    bool dodef[2] = {true, true};
#pragma unroll
    for (int qs = 0; qs < 2; ++qs) {
      if (qs == 0 && !act0) continue;
      const bool diag = qs ? diag1 : diag0;
      float sv[16];
#pragma unroll
      for (int tt = 0; tt < 4; ++tt)
#pragma unroll
        for (int rg = 0; rg < 4; ++rg) {
          float s = st[qs][tt][rg];  // raw score (scale folded into exp)
          if (diag && (t0 + tt * 16 + g * 4 + rg > qrow[qs])) s = -1e30f;
          sv[tt * 4 + rg] = s;
        }
      float h0 = fmaxf(fmaxf(fmaxf(sv[0], sv[1]), fmaxf(sv[2], sv[3])),
                       fmaxf(fmaxf(sv[4], sv[5]), fmaxf(sv[6], sv[7])));
      float h1 = fmaxf(fmaxf(fmaxf(sv[8], sv[9]), fmaxf(sv[10], sv[11])),
                       fmaxf(fmaxf(sv[12], sv[13]), fmaxf(sv[14], sv[15])));
      const float pmax = fmaxf(h0, h1);
      const bool defer = __all(pmax - m_i[qs] <= 64.f);  // T13: 64 raw == 8 scaled
      float corr = 1.f;
      if (!defer) {
        float mx = fmaxf(pmax, m_i[qs]);
        mx = fmaxf(mx, __shfl_xor(mx, 16, 64));
        mx = fmaxf(mx, __shfl_xor(mx, 32, 64));
        corr = __expf((m_i[qs] - mx) * 0.125f);
        m_i[qs] = mx;
      }
      dodef[qs] = defer;
      corr_bits[qs] = __float_as_uint(corr);
      const float m8 = m_i[qs] * 0.125f;
      float p[16];
      float rs = 0.f;
#pragma unroll
      for (int i = 0; i < 16; ++i) {
        p[i] = __expf(__builtin_fmaf(sv[i], 0.125f, -m8));
        rs += p[i];
      }
      rs += __shfl_xor(rs, 16, 64);
      rs += __shfl_xor(rs, 32, 64);
      l_i[qs] = l_i[qs] * corr + rs;
      // pack pairs: c[tt][e] covers kv pair (16tt + 4g + 2e)
      unsigned cw[4][2];
#pragma unroll
      for (int tt = 0; tt < 4; ++tt)
#pragma unroll
        for (int e = 0; e < 2; ++e)
          asm("v_cvt_pk_bf16_f32 %0, %1, %2"
              : "=v"(cw[tt][e]) : "v"(p[tt * 4 + 2 * e]), "v"(p[tt * 4 + 2 * e + 1]));
      // redistribute to A-frag words
#pragma unroll
      for (int kk = 0; kk < 2; ++kk) {
        unsigned x0 = cw[2 * kk][0], y0 = cw[2 * kk + 1][0];
        unsigned x1 = cw[2 * kk][1], y1 = cw[2 * kk + 1][1];
        asm volatile("v_permlane32_swap_b32 %0, %1" : "+v"(x0), "+v"(y0));
        asm volatile("v_permlane16_swap_b32 %0, %1" : "+v"(x0), "+v"(y0));
        asm volatile("v_permlane32_swap_b32 %0, %1" : "+v"(x1), "+v"(y1));
        asm volatile("v_permlane16_swap_b32 %0, %1" : "+v"(x1), "+v"(y1));
        uint4v w = {x0, x1, y0, y1};  // kv pairs (8g+0),(8g+2),(8g+4),(8g+6)
        pf[qs][kk] = *(bf16x8*)&w;
      }
    }
    // O rescale (rows live at lanes r'=4g+rr; corr per-lane at r) — only when needed
#pragma unroll
    for (int qs = 0; qs < 2; ++qs) {
      if (qs == 0 && !act0) continue;
      if (!dodef[qs]) {
        const float corr = __uint_as_float(corr_bits[qs]);
#pragma unroll
        for (int rr = 0; rr < 4; ++rr) {
          const float c = __shfl(corr, g * 4 + rr, 64);
#pragma unroll
          for (int nt = 0; nt < 4; ++nt) o[qs][nt][rr] *= c;
        }
      }
    }

    // O += P V
    __builtin_amdgcn_s_setprio(1);
#pragma unroll
    for (int kk = 0; kk < 2; ++kk)
#pragma unroll
      for (int nt = 0; nt < 4; ++nt) {
        const int row = nt * 16 + r, cc = kk * 4 + g;
        const bf16x8 vf = *(const bf16x8*)&lVt[cur][(row * 8 + (cc ^ (row & 7))) * 8];
        o[1][nt] = __builtin_amdgcn_mfma_f32_16x16x32_bf16(pf[1][kk], vf, o[1][nt], 0, 0, 0);
        if (act0)
          o[0][nt] = __builtin_amdgcn_mfma_f32_16x16x32_bf16(pf[0][kk], vf, o[0][nt], 0, 0, 0);
      }
    __builtin_amdgcn_s_setprio(0);
  }

#pragma unroll
  for (int qs = 0; qs < 2; ++qs) {
    float linv[4];
#pragma unroll
    for (int rr = 0; rr < 4; ++rr)
      linv[rr] = 1.f / __shfl(l_i[qs], g * 4 + rr, 64);
#pragma unroll
    for (int nt = 0; nt < 4; ++nt)
#pragma unroll
      for (int rr = 0; rr < 4; ++rr) {
        const long s = q0 + qs * 64 + wid * 16 + g * 4 + rr;
        out[((long)b * S_ + s) * 1024 + h * 64 + nt * 16 + r] = f2bf(o[qs][nt][rr] * linv[rr]);
      }
  }
}

extern "C" void kernel_launch(void* const* d_in, const int* in_sizes, int n_in,
                              void* d_out, int out_size, void* d_ws, size_t ws_size,
                              hipStream_t stream) {
  const float* x = (const float*)d_in[0];
  const float* Wq = (const float*)d_in[1];
  const float* Wk = (const float*)d_in[2];
  const float* Wv = (const float*)d_in[3];
  const float* Wo = (const float*)d_in[4];
  const float* bo = (const float*)d_in[5];
  float* out = (float*)d_out;

  char* ws = (char*)d_ws;
  unsigned short* Xb = (unsigned short*)(ws);                        // 16 MiB: x bf16 [8192][1024]
  unsigned short* Wt = (unsigned short*)(ws + (16ul << 20));         //  6 MiB: qkv weight B^T [3072][1024]
  unsigned short* Wob = (unsigned short*)(ws + (22ul << 20));        //  2 MiB: Wo bf16 [1024][1024]
  unsigned short* QK = (unsigned short*)(ws + (24ul << 20));         // 32 MiB: [8192][2048]
  unsigned short* VT = (unsigned short*)(ws + (56ul << 20));         // 16 MiB: [B*H*64][2048]
  unsigned short* AO = (unsigned short*)(ws + (72ul << 20));         // 16 MiB: attn out [8192][1024]

  pack_x_k<<<2048, 256, 0, stream>>>(x, Xb, (B_ * S_ * D_) / 4);
  pack_x_k<<<512, 256, 0, stream>>>(Wo, Wob, (D_ * D_) / 4);
  pack_wqkv_k<<<(3 * D_ * D_) / 256, 256, 0, stream>>>(Wq, Wk, Wv, Wt);

  gemm256_k<<<dim3(32, 24), 512, 0, stream>>>(Xb, Wt, QK, VT, B_ * S_, 3 * D_, D_);
  attn_k<<<dim3(64, 16), 256, 0, stream>>>(QK, VT, AO);
  gemm_bt_k<<<dim3(64, 8), 256, 0, stream>>>(AO, Wob, out, bo, B_ * S_, D_, D_);
}

// Round 14
// 190.279 us; speedup vs baseline: 1.0220x; 1.0097x over previous
//
#include <hip/hip_runtime.h>
#include <hip/hip_bf16.h>

typedef __bf16 bf16x8 __attribute__((ext_vector_type(8)));
typedef float f32x4 __attribute__((ext_vector_type(4)));
typedef unsigned short u16x4 __attribute__((ext_vector_type(4)));
typedef unsigned short u16x8 __attribute__((ext_vector_type(8)));
typedef unsigned uint4v __attribute__((ext_vector_type(4)));

#define B_ 4
#define S_ 2048
#define D_ 1024
#define H_ 16
#define HD_ 64

__device__ __forceinline__ unsigned short f2bf(float f) {
  unsigned u = __float_as_uint(f);
  u += 0x7fff + ((u >> 16) & 1);   // round-to-nearest-even
  return (unsigned short)(u >> 16);
}

__device__ __forceinline__ void gload16(const void* g, void* l) {
  __builtin_amdgcn_global_load_lds((const __attribute__((address_space(1))) unsigned int*)g,
                                   (__attribute__((address_space(3))) unsigned int*)l,
                                   16, 0, 0);
}

// ---------------- pack kernels ----------------
__global__ void pack_x_k(const float* __restrict__ in, unsigned short* __restrict__ out, int n4) {
  int i = blockIdx.x * blockDim.x + threadIdx.x;
  int stride = gridDim.x * blockDim.x;
  for (; i < n4; i += stride) {
    float4 v = reinterpret_cast<const float4*>(in)[i];
    u16x4 o = {f2bf(v.x), f2bf(v.y), f2bf(v.z), f2bf(v.w)};
    reinterpret_cast<u16x4*>(out)[i] = o;
  }
}

// Wq/Wk/Wv [H][D][HD] f32 -> Wt [3*D][D] bf16, Wt[h*64+e (+1024/2048)][d] = W[h][d][e]
__global__ void pack_wqkv_k(const float* __restrict__ Wq, const float* __restrict__ Wk,
                            const float* __restrict__ Wv, unsigned short* __restrict__ Wt) {
  int o = blockIdx.x * blockDim.x + threadIdx.x;  // 0 .. 3*1024*1024-1
  int n = o >> 10;
  int d = o & 1023;
  const float* W = (n < 1024) ? Wq : (n < 2048) ? Wk : Wv;
  int nn = n & 1023;
  int h = nn >> 6, e = nn & 63;
  Wt[o] = f2bf(W[(h << 16) + (d << 6) + e]);
}

// ---------------- 256x256 4-phase dedup GEMM (QKV proj) ----------------
// Round-6/11 proven K-loop: phase order (0,0),(0,1),(1,1),(1,0) with persistent
// reg fragments -> 24 ds_read_b128/wave/K-tile (the minimum); staging A0,B0@ph0,
// B1@ph1, A1@ph2 of t+1; counted waits vmcnt(6)/(6)/-/(4), never 0 mid-loop.
// Epilogue (round-13): cols [0,2048) -> QK[row][col]; cols [2048,3072) ->
// VT[((b*16+h)*64+e)][s] transposed (u16x4, block-uniform branch).
__global__ __launch_bounds__(512, 2) void gemm256_k(const unsigned short* __restrict__ A,
                                                    const unsigned short* __restrict__ Bt,
                                                    unsigned short* __restrict__ QK,
                                                    unsigned short* __restrict__ VT,
                                                    int M, int N, int K) {
  __shared__ __align__(16) unsigned short lds[2][2][2][128 * 64];  // [buf][op][half]
  const int tid = threadIdx.x;
  const int wid = tid >> 6, lane = tid & 63;
  const int r = lane & 15, g = lane >> 4;
  const int wm = wid >> 2, wn = wid & 3;

  // XCD-locality map (grid 32x12): per-XCD 8 arows x 6 bcols
  const int i_hw = blockIdx.y * gridDim.x + blockIdx.x;
  const int xcd = i_hw & 7, j = i_hw >> 3;          // j in 0..47
  const long arow0 = (long)((xcd & 3) * 8 + (j & 7)) * 256;
  const long bcol0 = (long)((xcd >> 2) * 6 + (j >> 3)) * 256;

  const f32x4 z4 = {0.f, 0.f, 0.f, 0.f};
  f32x4 acc[8][4];
#pragma unroll
  for (int m = 0; m < 8; ++m)
#pragma unroll
    for (int n = 0; n < 4; ++n) acc[m][n] = z4;

  auto stage_half = [&](int kt, int op, int h) {
    const unsigned short* src = op ? Bt + (bcol0 + 128 * h) * K : A + (arow0 + 128 * h) * K;
    const int k0 = kt << 6;
    unsigned short* base = &lds[kt & 1][op][h][0];
#pragma unroll
    for (int c = 0; c < 2; ++c) {
      const int jj = c * 512 + (wid << 6) + lane;  // 16B chunk id 0..1023
      const int row = jj >> 3, cc = jj & 7;
      const int ccs = cc ^ (row & 7);              // pre-swizzled global source chunk
      gload16(src + (long)row * K + k0 + ccs * 8, base + (c * 512 + (wid << 6)) * 8);
    }
  };

  bf16x8 af[4][2], bv0[2][2], bv1[2][2];
  auto read_a = [&](int buf, int mh) {
#pragma unroll
    for (int i2 = 0; i2 < 4; ++i2)
#pragma unroll
      for (int kk = 0; kk < 2; ++kk) {
        const int rowh = (2 * i2 + wm) * 16 + r;
        af[i2][kk] = *(const bf16x8*)&lds[buf][0][mh][rowh * 64 + (((kk << 2) + g) ^ (rowh & 7)) * 8];
      }
  };
  auto read_b = [&](bf16x8 (&bv)[2][2], int buf, int nh) {
#pragma unroll
    for (int j2 = 0; j2 < 2; ++j2)
#pragma unroll
      for (int kk = 0; kk < 2; ++kk) {
        const int rowh = (4 * j2 + wn) * 16 + r;
        bv[j2][kk] = *(const bf16x8*)&lds[buf][1][nh][rowh * 64 + (((kk << 2) + g) ^ (rowh & 7)) * 8];
      }
  };
  auto mma_q = [&](bf16x8 (&bv)[2][2], int mh, int nh) {
    __builtin_amdgcn_s_setprio(1);
#pragma unroll
    for (int kk = 0; kk < 2; ++kk)
#pragma unroll
      for (int i2 = 0; i2 < 4; ++i2)
#pragma unroll
        for (int j2 = 0; j2 < 2; ++j2)
          acc[4 * mh + i2][2 * nh + j2] = __builtin_amdgcn_mfma_f32_16x16x32_bf16(
              af[i2][kk], bv[j2][kk], acc[4 * mh + i2][2 * nh + j2], 0, 0, 0);
    __builtin_amdgcn_s_setprio(0);
  };

  const int nk = K >> 6;
  // prologue: A0(0), B0(0), B1(0), A1(0)
  stage_half(0, 0, 0);
  stage_half(0, 1, 0);
  stage_half(0, 1, 1);
  stage_half(0, 0, 1);
  asm volatile("s_waitcnt vmcnt(4)" ::: "memory");  // A0(0),B0(0) landed
  asm volatile("s_barrier" ::: "memory");

  for (int t = 0; t < nk; ++t) {
    const int buf = t & 1;
    const bool pre = (t + 1 < nk);
    // ---- phase (0,0): read af0 (8) + bv0 (4); stage A0,B0 of t+1
    read_a(buf, 0);
    read_b(bv0, buf, 0);
    if (pre) { stage_half(t + 1, 0, 0); stage_half(t + 1, 1, 0); }
    asm volatile("s_barrier" ::: "memory");
    mma_q(bv0, 0, 0);
    if (pre) asm volatile("s_waitcnt vmcnt(6)" ::: "memory");   // B1(t) landed
    else     asm volatile("s_waitcnt vmcnt(2)" ::: "memory");
    asm volatile("s_waitcnt lgkmcnt(0)\n\ts_barrier" ::: "memory");
    // ---- phase (0,1): read bv1 (4); stage B1 of t+1
    read_b(bv1, buf, 1);
    if (pre) stage_half(t + 1, 1, 1);
    asm volatile("s_barrier" ::: "memory");
    mma_q(bv1, 0, 1);
    if (pre) asm volatile("s_waitcnt vmcnt(6)" ::: "memory");   // A1(t) landed
    else     asm volatile("s_waitcnt vmcnt(0)" ::: "memory");
    asm volatile("s_waitcnt lgkmcnt(0)\n\ts_barrier" ::: "memory");
    // ---- phase (1,1): read af1 (8); stage A1 of t+1
    read_a(buf, 1);
    if (pre) stage_half(t + 1, 0, 1);
    asm volatile("s_barrier" ::: "memory");
    mma_q(bv1, 1, 1);
    asm volatile("s_waitcnt lgkmcnt(0)\n\ts_barrier" ::: "memory");
    // ---- phase (1,0): pure MFMA (af1 x bv0 from registers)
    asm volatile("s_barrier" ::: "memory");
    mma_q(bv0, 1, 0);
    if (pre) asm volatile("s_waitcnt vmcnt(4)" ::: "memory");   // A0,B0 of t+1 landed
    asm volatile("s_waitcnt lgkmcnt(0)\n\ts_barrier" ::: "memory");
  }

  if (bcol0 < 2048) {
    // Q|K columns: row-major [8192][2048]
#pragma unroll
    for (int m = 0; m < 8; ++m)
#pragma unroll
      for (int n = 0; n < 4; ++n)
#pragma unroll
        for (int rr = 0; rr < 4; ++rr) {
          const long row = arow0 + (2 * m + wm) * 16 + g * 4 + rr;
          const long col = bcol0 + (4 * n + wn) * 16 + r;
          QK[row * 2048 + col] = f2bf(acc[m][n][rr]);
        }
  } else {
    // V columns: write transposed VT[((b*16+h)*64+e)][s], 4 consecutive tokens/lane
#pragma unroll
    for (int m = 0; m < 8; ++m) {
      const long row0 = arow0 + (2 * m + wm) * 16 + g * 4;  // 4 consecutive rows
      const long b = row0 >> 11, s = row0 & 2047;           // no b-crossing (256|2048)
#pragma unroll
      for (int n = 0; n < 4; ++n) {
        const long vcol = bcol0 - 2048 + (4 * n + wn) * 16 + r;
        const long h = vcol >> 6, e = vcol & 63;
        u16x4 w4;
#pragma unroll
        for (int rr = 0; rr < 4; ++rr) w4[rr] = f2bf(acc[m][n][rr]);
        *(u16x4*)&VT[(((b << 4) + h) * 64 + e) * 2048 + s] = w4;
      }
    }
  }
}

// ---------------- 128x128 GEMM (out-proj): C = A * Bt^T + bias, f32 out ----------------
__global__ __launch_bounds__(256, 2) void gemm_bt_k(const unsigned short* __restrict__ A,
                                                    const unsigned short* __restrict__ Bt,
                                                    float* __restrict__ C,
                                                    const float* __restrict__ bias,
                                                    int M, int N, int K) {
  __shared__ __align__(16) unsigned short lA[2][128 * 64];
  __shared__ __align__(16) unsigned short lB[2][128 * 64];
  const int tid = threadIdx.x;
  const int wid = tid >> 6, lane = tid & 63;
  const int r = lane & 15, g = lane >> 4;
  const long arow0 = (long)blockIdx.x * 128;
  const long brow0 = (long)blockIdx.y * 128;
  const int wr = (wid >> 1) * 64, wc = (wid & 1) * 64;

  const f32x4 z4 = {0.f, 0.f, 0.f, 0.f};
  f32x4 acc[4][4];
#pragma unroll
  for (int m = 0; m < 4; ++m)
#pragma unroll
    for (int n = 0; n < 4; ++n) acc[m][n] = z4;

  auto stage = [&](int buf, int k0) {
#pragma unroll
    for (int c = 0; c < 4; ++c) {
      const int j = c * 256 + wid * 64 + lane;
      const int row = j >> 3, col = (j & 7) * 8;
      gload16(A + (arow0 + row) * K + k0 + col, &lA[buf][(c * 256 + wid * 64) * 8]);
      gload16(Bt + (brow0 + row) * K + k0 + col, &lB[buf][(c * 256 + wid * 64) * 8]);
    }
  };

  stage(0, 0);
  __syncthreads();
  const int nk = K >> 6;
  for (int kt = 0; kt < nk; ++kt) {
    const int cur = kt & 1;
    if (kt + 1 < nk) stage(cur ^ 1, (kt + 1) << 6);
#pragma unroll
    for (int kk = 0; kk < 2; ++kk) {
      bf16x8 af[4], bfr[4];
#pragma unroll
      for (int m = 0; m < 4; ++m)
        af[m] = *(const bf16x8*)&lA[cur][(wr + m * 16 + r) * 64 + kk * 32 + g * 8];
#pragma unroll
      for (int n = 0; n < 4; ++n)
        bfr[n] = *(const bf16x8*)&lB[cur][(wc + n * 16 + r) * 64 + kk * 32 + g * 8];
#pragma unroll
      for (int m = 0; m < 4; ++m)
#pragma unroll
        for (int n = 0; n < 4; ++n)
          acc[m][n] = __builtin_amdgcn_mfma_f32_16x16x32_bf16(af[m], bfr[n], acc[m][n], 0, 0, 0);
    }
    __syncthreads();
  }

#pragma unroll
  for (int m = 0; m < 4; ++m) {
#pragma unroll
    for (int n = 0; n < 4; ++n) {
#pragma unroll
      for (int rr = 0; rr < 4; ++rr) {
        const long row = arow0 + wr + m * 16 + g * 4 + rr;
        const long col = brow0 + wc + n * 16 + r;
        C[row * N + col] = acc[m][n][rr] + bias[col];
      }
    }
  }
}

// ---------------- flash attention (round-13, passing) ----------------
// qk: [B*S][2048] bf16 (q|k per head); vt: [B][H][64][2048] bf16 (V transposed).
// Both lK and lVt staged directly via global_load_lds (pre-swizzled source chunk,
// linear dest). Swapped QK^T -> per-lane softmax raw-score domain; cvt_pk+permlane.
__global__ __launch_bounds__(256, 2) void attn_k(const unsigned short* __restrict__ qk,
                                                 const unsigned short* __restrict__ vt,
                                                 unsigned short* __restrict__ out) {
  __shared__ __align__(16) unsigned short lK[2][64 * 64];
  __shared__ __align__(16) unsigned short lVt[2][64 * 64];

  const int tid = threadIdx.x, wid = tid >> 6, lane = tid & 63;
  const int r = lane & 15, g = lane >> 4;
  const int bh = blockIdx.x;
  const int b = bh >> 4, h = bh & 15;
  const int qb = 15 - (int)blockIdx.y;   // long blocks dispatch first
  const int q0 = qb * 128;

  const unsigned short* Qg = qk + ((long)b * S_) * 2048 + h * 64;
  const unsigned short* Kg = Qg + 1024;
  const unsigned short* Vg = vt + ((long)(b * 16 + h)) * 64 * 2048;  // [e][s]

  // Q fragments for both subtiles
  int qrow[2];
  bf16x8 qf[2][2];
#pragma unroll
  for (int qs = 0; qs < 2; ++qs) {
    qrow[qs] = q0 + qs * 64 + wid * 16 + r;
#pragma unroll
    for (int kk = 0; kk < 2; ++kk)
      qf[qs][kk] = *(const bf16x8*)&Qg[(long)qrow[qs] * 2048 + kk * 32 + g * 8];
  }

  const f32x4 z4 = {0.f, 0.f, 0.f, 0.f};
  f32x4 o[2][4];
#pragma unroll
  for (int qs = 0; qs < 2; ++qs)
#pragma unroll
    for (int nt = 0; nt < 4; ++nt) o[qs][nt] = z4;
  float m_i[2] = {-1e30f, -1e30f};
  float l_i[2] = {0.f, 0.f};

  auto stage = [&](int buf, int t0) {
#pragma unroll
    for (int c = 0; c < 2; ++c) {
      const int j = c * 256 + tid;           // chunk id 0..511
      const int row = j >> 3, cc = j & 7;
      const int ccs = (cc ^ (row & 7)) << 3; // source element offset
      gload16(Kg + (long)(t0 + row) * 2048 + ccs, &lK[buf][j * 8]);
      gload16(Vg + (long)row * 2048 + t0 + ccs, &lVt[buf][j * 8]);
    }
  };

  const int ntiles = (q0 >> 6) + 2;  // kv tiles 0 .. q0/64+1
  stage(0, 0);

  for (int t = 0; t < ntiles; ++t) {
    const int cur = t & 1;
    __syncthreads();                              // drains vmcnt: lds[cur] ready;
                                                  // all waves done reading cur^1
    if (t + 1 < ntiles) stage(cur ^ 1, (t + 1) << 6);

    const int t0 = t << 6;
    const bool act0 = (t < ntiles - 1);   // qs=0 rows all < q0+64
    const bool diag0 = (t == ntiles - 2); // t0 == q0
    const bool diag1 = (t == ntiles - 1); // t0 == q0+64

    // S^T = K Q^T (swapped operands): st[qs][tt][rg] = S_raw[qrow[qs]][t0+16tt+4g+rg]
    f32x4 st[2][4];
#pragma unroll
    for (int tt = 0; tt < 4; ++tt) { st[0][tt] = z4; st[1][tt] = z4; }
    __builtin_amdgcn_s_setprio(1);
#pragma unroll
    for (int kk = 0; kk < 2; ++kk)
#pragma unroll
      for (int tt = 0; tt < 4; ++tt) {
        const int row = tt * 16 + r, cc = kk * 4 + g;
        bf16x8 kf = *(const bf16x8*)&lK[cur][(row * 8 + (cc ^ (row & 7))) * 8];
        st[1][tt] = __builtin_amdgcn_mfma_f32_16x16x32_bf16(kf, qf[1][kk], st[1][tt], 0, 0, 0);
        if (act0)
          st[0][tt] = __builtin_amdgcn_mfma_f32_16x16x32_bf16(kf, qf[0][kk], st[0][tt], 0, 0, 0);
      }
    __builtin_amdgcn_s_setprio(0);

    // per-lane softmax + in-register P repack, per active subtile
    bf16x8 pf[2][2];
    unsigned corr_bits[2] = {0x3f800000u, 0x3f800000u};
    bool dodef[2] = {true, true};
#pragma unroll
    for (int qs = 0; qs < 2; ++qs) {
      if (qs == 0 && !act0) continue;
      const bool diag = qs ? diag1 : diag0;
      float sv[16];
#pragma unroll
      for (int tt = 0; tt < 4; ++tt)
#pragma unroll
        for (int rg = 0; rg < 4; ++rg) {
          float s = st[qs][tt][rg];  // raw score (scale folded into exp)
          if (diag && (t0 + tt * 16 + g * 4 + rg > qrow[qs])) s = -1e30f;
          sv[tt * 4 + rg] = s;
        }
      float h0 = fmaxf(fmaxf(fmaxf(sv[0], sv[1]), fmaxf(sv[2], sv[3])),
                       fmaxf(fmaxf(sv[4], sv[5]), fmaxf(sv[6], sv[7])));
      float h1 = fmaxf(fmaxf(fmaxf(sv[8], sv[9]), fmaxf(sv[10], sv[11])),
                       fmaxf(fmaxf(sv[12], sv[13]), fmaxf(sv[14], sv[15])));
      const float pmax = fmaxf(h0, h1);
      const bool defer = __all(pmax - m_i[qs] <= 64.f);  // T13: 64 raw == 8 scaled
      float corr = 1.f;
      if (!defer) {
        float mx = fmaxf(pmax, m_i[qs]);
        mx = fmaxf(mx, __shfl_xor(mx, 16, 64));
        mx = fmaxf(mx, __shfl_xor(mx, 32, 64));
        corr = __expf((m_i[qs] - mx) * 0.125f);
        m_i[qs] = mx;
      }
      dodef[qs] = defer;
      corr_bits[qs] = __float_as_uint(corr);
      const float m8 = m_i[qs] * 0.125f;
      float p[16];
      float rs = 0.f;
#pragma unroll
      for (int i = 0; i < 16; ++i) {
        p[i] = __expf(__builtin_fmaf(sv[i], 0.125f, -m8));
        rs += p[i];
      }
      rs += __shfl_xor(rs, 16, 64);
      rs += __shfl_xor(rs, 32, 64);
      l_i[qs] = l_i[qs] * corr + rs;
      // pack pairs: c[tt][e] covers kv pair (16tt + 4g + 2e)
      unsigned cw[4][2];
#pragma unroll
      for (int tt = 0; tt < 4; ++tt)
#pragma unroll
        for (int e = 0; e < 2; ++e)
          asm("v_cvt_pk_bf16_f32 %0, %1, %2"
              : "=v"(cw[tt][e]) : "v"(p[tt * 4 + 2 * e]), "v"(p[tt * 4 + 2 * e + 1]));
      // redistribute to A-frag words
#pragma unroll
      for (int kk = 0; kk < 2; ++kk) {
        unsigned x0 = cw[2 * kk][0], y0 = cw[2 * kk + 1][0];
        unsigned x1 = cw[2 * kk][1], y1 = cw[2 * kk + 1][1];
        asm volatile("v_permlane32_swap_b32 %0, %1" : "+v"(x0), "+v"(y0));
        asm volatile("v_permlane16_swap_b32 %0, %1" : "+v"(x0), "+v"(y0));
        asm volatile("v_permlane32_swap_b32 %0, %1" : "+v"(x1), "+v"(y1));
        asm volatile("v_permlane16_swap_b32 %0, %1" : "+v"(x1), "+v"(y1));
        uint4v w = {x0, x1, y0, y1};  // kv pairs (8g+0),(8g+2),(8g+4),(8g+6)
        pf[qs][kk] = *(bf16x8*)&w;
      }
    }
    // O rescale (rows live at lanes r'=4g+rr; corr per-lane at r) — only when needed
#pragma unroll
    for (int qs = 0; qs < 2; ++qs) {
      if (qs == 0 && !act0) continue;
      if (!dodef[qs]) {
        const float corr = __uint_as_float(corr_bits[qs]);
#pragma unroll
        for (int rr = 0; rr < 4; ++rr) {
          const float c = __shfl(corr, g * 4 + rr, 64);
#pragma unroll
          for (int nt = 0; nt < 4; ++nt) o[qs][nt][rr] *= c;
        }
      }
    }

    // O += P V
    __builtin_amdgcn_s_setprio(1);
#pragma unroll
    for (int kk = 0; kk < 2; ++kk)
#pragma unroll
      for (int nt = 0; nt < 4; ++nt) {
        const int row = nt * 16 + r, cc = kk * 4 + g;
        const bf16x8 vf = *(const bf16x8*)&lVt[cur][(row * 8 + (cc ^ (row & 7))) * 8];
        o[1][nt] = __builtin_amdgcn_mfma_f32_16x16x32_bf16(pf[1][kk], vf, o[1][nt], 0, 0, 0);
        if (act0)
          o[0][nt] = __builtin_amdgcn_mfma_f32_16x16x32_bf16(pf[0][kk], vf, o[0][nt], 0, 0, 0);
      }
    __builtin_amdgcn_s_setprio(0);
  }

#pragma unroll
  for (int qs = 0; qs < 2; ++qs) {
    float linv[4];
#pragma unroll
    for (int rr = 0; rr < 4; ++rr)
      linv[rr] = 1.f / __shfl(l_i[qs], g * 4 + rr, 64);
#pragma unroll
    for (int nt = 0; nt < 4; ++nt)
#pragma unroll
      for (int rr = 0; rr < 4; ++rr) {
        const long s = q0 + qs * 64 + wid * 16 + g * 4 + rr;
        out[((long)b * S_ + s) * 1024 + h * 64 + nt * 16 + r] = f2bf(o[qs][nt][rr] * linv[rr]);
      }
  }
}

extern "C" void kernel_launch(void* const* d_in, const int* in_sizes, int n_in,
                              void* d_out, int out_size, void* d_ws, size_t ws_size,
                              hipStream_t stream) {
  const float* x = (const float*)d_in[0];
  const float* Wq = (const float*)d_in[1];
  const float* Wk = (const float*)d_in[2];
  const float* Wv = (const float*)d_in[3];
  const float* Wo = (const float*)d_in[4];
  const float* bo = (const float*)d_in[5];
  float* out = (float*)d_out;

  char* ws = (char*)d_ws;
  unsigned short* Xb = (unsigned short*)(ws);                        // 16 MiB: x bf16 [8192][1024]
  unsigned short* Wt = (unsigned short*)(ws + (16ul << 20));         //  6 MiB: qkv weight B^T [3072][1024]
  unsigned short* Wob = (unsigned short*)(ws + (22ul << 20));        //  2 MiB: Wo bf16 [1024][1024]
  unsigned short* QK = (unsigned short*)(ws + (24ul << 20));         // 32 MiB: [8192][2048]
  unsigned short* VT = (unsigned short*)(ws + (56ul << 20));         // 16 MiB: [B*H*64][2048]
  unsigned short* AO = (unsigned short*)(ws + (72ul << 20));         // 16 MiB: attn out [8192][1024]

  pack_x_k<<<2048, 256, 0, stream>>>(x, Xb, (B_ * S_ * D_) / 4);
  pack_x_k<<<512, 256, 0, stream>>>(Wo, Wob, (D_ * D_) / 4);
  pack_wqkv_k<<<(3 * D_ * D_) / 256, 256, 0, stream>>>(Wq, Wk, Wv, Wt);

  gemm256_k<<<dim3(32, 12), 512, 0, stream>>>(Xb, Wt, QK, VT, B_ * S_, 3 * D_, D_);
  attn_k<<<dim3(64, 16), 256, 0, stream>>>(QK, VT, AO);
  gemm_bt_k<<<dim3(64, 8), 256, 0, stream>>>(AO, Wob, out, bo, B_ * S_, D_, D_);
}

// Round 15
// 178.779 us; speedup vs baseline: 1.0877x; 1.0643x over previous
//
#include <hip/hip_runtime.h>
#include <hip/hip_bf16.h>

typedef __bf16 bf16x8 __attribute__((ext_vector_type(8)));
typedef float f32x4 __attribute__((ext_vector_type(4)));
typedef unsigned short u16x4 __attribute__((ext_vector_type(4)));
typedef unsigned short u16x8 __attribute__((ext_vector_type(8)));
typedef unsigned uint4v __attribute__((ext_vector_type(4)));

#define B_ 4
#define S_ 2048
#define D_ 1024
#define H_ 16
#define HD_ 64

__device__ __forceinline__ unsigned short f2bf(float f) {
  unsigned u = __float_as_uint(f);
  u += 0x7fff + ((u >> 16) & 1);   // round-to-nearest-even
  return (unsigned short)(u >> 16);
}

__device__ __forceinline__ void gload16(const void* g, void* l) {
  __builtin_amdgcn_global_load_lds((const __attribute__((address_space(1))) unsigned int*)g,
                                   (__attribute__((address_space(3))) unsigned int*)l,
                                   16, 0, 0);
}

// ---------------- pack kernels ----------------
__global__ void pack_x_k(const float* __restrict__ in, unsigned short* __restrict__ out, int n4) {
  int i = blockIdx.x * blockDim.x + threadIdx.x;
  int stride = gridDim.x * blockDim.x;
  for (; i < n4; i += stride) {
    float4 v = reinterpret_cast<const float4*>(in)[i];
    u16x4 o = {f2bf(v.x), f2bf(v.y), f2bf(v.z), f2bf(v.w)};
    reinterpret_cast<u16x4*>(out)[i] = o;
  }
}

// Wq/Wk/Wv [H][D][HD] f32 -> Wt [3*D][D] bf16, Wt[h*64+e (+1024/2048)][d] = W[h][d][e]
__global__ void pack_wqkv_k(const float* __restrict__ Wq, const float* __restrict__ Wk,
                            const float* __restrict__ Wv, unsigned short* __restrict__ Wt) {
  int o = blockIdx.x * blockDim.x + threadIdx.x;  // 0 .. 3*1024*1024-1
  int n = o >> 10;
  int d = o & 1023;
  const float* W = (n < 1024) ? Wq : (n < 2048) ? Wk : Wv;
  int nn = n & 1023;
  int h = nn >> 6, e = nn & 63;
  Wt[o] = f2bf(W[(h << 16) + (d << 6) + e]);
}

// ---------------- 256x192 2-phase GEMM (QKV proj) ----------------
// 512 threads = 8 waves (2M x 4N); per-wave output 128x48 (m-blocks 2i+wm,
// n-blocks 4j+wn, j<3). BK=64. LDS 112 KiB = 2buf x {A0,A1: 128x64, B: 192x64}.
// Grid 32x16 = 512 blocks = exactly 2 even dispatch rounds on 256 CUs.
// T2 chunk swizzle pos = cc ^ (row&7) via linear gload_lds dest + pre-swz source.
// ph0 {read A0(8)+B(6); stage A0,B(t+1); barrier; 24 MFMA; vmcnt(5)} ;
// ph1 {read A1(8); stage A1(t+1); barrier; 24 MFMA; vmcnt(2)}. Tail drains 0.
// Epilogue: 16-col blocks < 2048 -> QK[row][col]; >= 2048 -> VT transposed.
__global__ __launch_bounds__(512, 2) void gemm256_k(const unsigned short* __restrict__ A,
                                                    const unsigned short* __restrict__ Bt,
                                                    unsigned short* __restrict__ QK,
                                                    unsigned short* __restrict__ VT,
                                                    int M, int N, int K) {
  __shared__ __align__(16) unsigned short lA0[2][128 * 64];
  __shared__ __align__(16) unsigned short lA1[2][128 * 64];
  __shared__ __align__(16) unsigned short lB[2][192 * 64];
  const int tid = threadIdx.x;
  const int wid = tid >> 6, lane = tid & 63;
  const int r = lane & 15, g = lane >> 4;
  const int wm = wid >> 2, wn = wid & 3;

  // XCD-locality map (grid 32x16 = 512 = 8 XCD x 64): per-XCD 8 arows x 8 bcols
  const int i_hw = blockIdx.y * gridDim.x + blockIdx.x;
  const int xcd = i_hw & 7, j = i_hw >> 3;          // j in 0..63
  const long arow0 = (long)((xcd & 3) * 8 + (j & 7)) * 256;
  const long bcol0 = (long)((xcd >> 2) * 8 + (j >> 3)) * 192;

  const f32x4 z4 = {0.f, 0.f, 0.f, 0.f};
  f32x4 acc[8][3];
#pragma unroll
  for (int m = 0; m < 8; ++m)
#pragma unroll
    for (int n = 0; n < 3; ++n) acc[m][n] = z4;

  // which = 0 (A rows 0..127), 1 (A rows 128..255), 2 (B, 192 rows)
  auto stage_half = [&](int kt, int which) {
    const unsigned short* src = (which == 2) ? Bt + bcol0 * K : A + (arow0 + 128 * which) * K;
    const int k0 = kt << 6;
    unsigned short* base = (which == 0) ? &lA0[kt & 1][0]
                         : (which == 1) ? &lA1[kt & 1][0] : &lB[kt & 1][0];
    const int nch = (which == 2) ? 3 : 2;
    for (int c = 0; c < nch; ++c) {
      const int jj = c * 512 + tid;                // 16B chunk id
      const int row = jj >> 3, cc = jj & 7;
      const int ccs = cc ^ (row & 7);              // pre-swizzled global source chunk
      gload16(src + (long)row * K + k0 + ccs * 8, base + jj * 8);
    }
  };

  bf16x8 af[4][2], bv[3][2];
  auto read_a = [&](const unsigned short* lbase) {  // 8 x ds_read_b128
#pragma unroll
    for (int i2 = 0; i2 < 4; ++i2)
#pragma unroll
      for (int kk = 0; kk < 2; ++kk) {
        const int rowh = (2 * i2 + wm) * 16 + r;
        af[i2][kk] = *(const bf16x8*)&lbase[rowh * 64 + (((kk << 2) + g) ^ (rowh & 7)) * 8];
      }
  };
  auto read_b = [&](int buf) {                      // 6 x ds_read_b128
#pragma unroll
    for (int j2 = 0; j2 < 3; ++j2)
#pragma unroll
      for (int kk = 0; kk < 2; ++kk) {
        const int rowh = (4 * j2 + wn) * 16 + r;
        bv[j2][kk] = *(const bf16x8*)&lB[buf][rowh * 64 + (((kk << 2) + g) ^ (rowh & 7)) * 8];
      }
  };
  auto mma_h = [&](int mh) {                        // 24 MFMA for one A-half
    __builtin_amdgcn_s_setprio(1);
#pragma unroll
    for (int kk = 0; kk < 2; ++kk)
#pragma unroll
      for (int i2 = 0; i2 < 4; ++i2)
#pragma unroll
        for (int j2 = 0; j2 < 3; ++j2)
          acc[4 * mh + i2][j2] = __builtin_amdgcn_mfma_f32_16x16x32_bf16(
              af[i2][kk], bv[j2][kk], acc[4 * mh + i2][j2], 0, 0, 0);
    __builtin_amdgcn_s_setprio(0);
  };

  const int nk = K >> 6;
  // prologue: A0(0) [+2], B(0) [+3], A1(0) [+2] -> out 7; need first 5
  stage_half(0, 0);
  stage_half(0, 2);
  stage_half(0, 1);
  asm volatile("s_waitcnt vmcnt(2)" ::: "memory");
  asm volatile("s_barrier" ::: "memory");

  for (int t = 0; t < nk; ++t) {
    const int buf = t & 1;
    const bool pre = (t + 1 < nk);
    // ---- phase 0: A-half 0 x all B
    read_a(&lA0[buf][0]);
    read_b(buf);
    if (pre) { stage_half(t + 1, 0); stage_half(t + 1, 2); }  // +5
    asm volatile("s_barrier" ::: "memory");
    mma_h(0);
    if (pre) asm volatile("s_waitcnt vmcnt(5)" ::: "memory");   // A1(t) landed
    else     asm volatile("s_waitcnt vmcnt(0)" ::: "memory");
    asm volatile("s_waitcnt lgkmcnt(0)\n\ts_barrier" ::: "memory");
    // ---- phase 1: A-half 1 (bv persist in registers)
    read_a(&lA1[buf][0]);
    if (pre) stage_half(t + 1, 1);                               // +2
    asm volatile("s_barrier" ::: "memory");
    mma_h(1);
    if (pre) asm volatile("s_waitcnt vmcnt(2)" ::: "memory");   // A0,B(t+1) landed
    asm volatile("s_waitcnt lgkmcnt(0)\n\ts_barrier" ::: "memory");
  }

  // epilogue: 16-col block (4*j2+wn) at bcol0 is uniformly QK (<2048) or V (>=2048)
#pragma unroll
  for (int j2 = 0; j2 < 3; ++j2) {
    const long colb = bcol0 + (4 * j2 + wn) * 16;  // 16-aligned; 2048 is 16-aligned
    if (colb < 2048) {
#pragma unroll
      for (int m = 0; m < 8; ++m)
#pragma unroll
        for (int rr = 0; rr < 4; ++rr) {
          const long row = arow0 + (2 * m + wm) * 16 + g * 4 + rr;
          QK[row * 2048 + colb + r] = f2bf(acc[m][j2][rr]);
        }
    } else {
      const long vcol = colb - 2048 + r;
      const long h = vcol >> 6, e = vcol & 63;
#pragma unroll
      for (int m = 0; m < 8; ++m) {
        const long row0 = arow0 + (2 * m + wm) * 16 + g * 4;  // 4 consecutive tokens
        const long b = row0 >> 11, s = row0 & 2047;           // no b-crossing (256|2048)
        u16x4 w4;
#pragma unroll
        for (int rr = 0; rr < 4; ++rr) w4[rr] = f2bf(acc[m][j2][rr]);
        *(u16x4*)&VT[(((b << 4) + h) * 64 + e) * 2048 + s] = w4;
      }
    }
  }
}

// ---------------- 256x128 2-phase GEMM (out-proj): C = A*Bt^T + bias, f32 out ----
// Round-13-verified structure; grid 32x8 = 256 blocks = 1 perfect dispatch round.
__global__ __launch_bounds__(512, 2) void gemm_op_k(const unsigned short* __restrict__ A,
                                                    const unsigned short* __restrict__ Bt,
                                                    float* __restrict__ C,
                                                    const float* __restrict__ bias,
                                                    int M, int N, int K) {
  __shared__ __align__(16) unsigned short lA0[2][128 * 64];
  __shared__ __align__(16) unsigned short lA1[2][128 * 64];
  __shared__ __align__(16) unsigned short lB[2][128 * 64];
  const int tid = threadIdx.x;
  const int wid = tid >> 6, lane = tid & 63;
  const int r = lane & 15, g = lane >> 4;
  const int wm = wid >> 2, wn = wid & 3;

  // XCD map (grid 32x8 = 256 = 8 XCD x 32): per-XCD 8 arows x 4 bcols
  const int i_hw = blockIdx.y * gridDim.x + blockIdx.x;
  const int xcd = i_hw & 7, j = i_hw >> 3;          // j in 0..31
  const long arow0 = (long)((xcd & 3) * 8 + (j & 7)) * 256;
  const long bcol0 = (long)((xcd >> 2) * 4 + (j >> 3)) * 128;

  const f32x4 z4 = {0.f, 0.f, 0.f, 0.f};
  f32x4 acc[8][2];
#pragma unroll
  for (int m = 0; m < 8; ++m)
#pragma unroll
    for (int n = 0; n < 2; ++n) acc[m][n] = z4;

  auto stage_half = [&](int kt, int which) {
    const unsigned short* src = (which == 2) ? Bt + bcol0 * K : A + (arow0 + 128 * which) * K;
    const int k0 = kt << 6;
    unsigned short* base = (which == 0) ? &lA0[kt & 1][0]
                         : (which == 1) ? &lA1[kt & 1][0] : &lB[kt & 1][0];
#pragma unroll
    for (int c = 0; c < 2; ++c) {
      const int jj = c * 512 + tid;
      const int row = jj >> 3, cc = jj & 7;
      const int ccs = cc ^ (row & 7);
      gload16(src + (long)row * K + k0 + ccs * 8, base + jj * 8);
    }
  };

  bf16x8 af[4][2], bv[2][2];
  auto read_a = [&](const unsigned short* lbase) {
#pragma unroll
    for (int i2 = 0; i2 < 4; ++i2)
#pragma unroll
      for (int kk = 0; kk < 2; ++kk) {
        const int rowh = (2 * i2 + wm) * 16 + r;
        af[i2][kk] = *(const bf16x8*)&lbase[rowh * 64 + (((kk << 2) + g) ^ (rowh & 7)) * 8];
      }
  };
  auto read_b = [&](int buf) {
#pragma unroll
    for (int j2 = 0; j2 < 2; ++j2)
#pragma unroll
      for (int kk = 0; kk < 2; ++kk) {
        const int rowh = (4 * j2 + wn) * 16 + r;
        bv[j2][kk] = *(const bf16x8*)&lB[buf][rowh * 64 + (((kk << 2) + g) ^ (rowh & 7)) * 8];
      }
  };
  auto mma_h = [&](int mh) {
    __builtin_amdgcn_s_setprio(1);
#pragma unroll
    for (int kk = 0; kk < 2; ++kk)
#pragma unroll
      for (int i2 = 0; i2 < 4; ++i2)
#pragma unroll
        for (int j2 = 0; j2 < 2; ++j2)
          acc[4 * mh + i2][j2] = __builtin_amdgcn_mfma_f32_16x16x32_bf16(
              af[i2][kk], bv[j2][kk], acc[4 * mh + i2][j2], 0, 0, 0);
    __builtin_amdgcn_s_setprio(0);
  };

  const int nk = K >> 6;
  stage_half(0, 0);
  stage_half(0, 2);
  stage_half(0, 1);
  asm volatile("s_waitcnt vmcnt(2)" ::: "memory");  // A0(0),B(0) landed
  asm volatile("s_barrier" ::: "memory");

  for (int t = 0; t < nk; ++t) {
    const int buf = t & 1;
    const bool pre = (t + 1 < nk);
    read_a(&lA0[buf][0]);
    read_b(buf);
    if (pre) { stage_half(t + 1, 0); stage_half(t + 1, 2); }
    asm volatile("s_barrier" ::: "memory");
    mma_h(0);
    if (pre) asm volatile("s_waitcnt vmcnt(4)" ::: "memory");   // A1(t) landed
    else     asm volatile("s_waitcnt vmcnt(0)" ::: "memory");
    asm volatile("s_waitcnt lgkmcnt(0)\n\ts_barrier" ::: "memory");
    read_a(&lA1[buf][0]);
    if (pre) stage_half(t + 1, 1);
    asm volatile("s_barrier" ::: "memory");
    mma_h(1);
    if (pre) asm volatile("s_waitcnt vmcnt(2)" ::: "memory");   // A0,B(t+1) landed
    asm volatile("s_waitcnt lgkmcnt(0)\n\ts_barrier" ::: "memory");
  }

#pragma unroll
  for (int m = 0; m < 8; ++m)
#pragma unroll
    for (int n = 0; n < 2; ++n)
#pragma unroll
      for (int rr = 0; rr < 4; ++rr) {
        const long row = arow0 + (2 * m + wm) * 16 + g * 4 + rr;
        const long col = bcol0 + (4 * n + wn) * 16 + r;
        C[row * N + col] = acc[m][n][rr] + bias[col];
      }
}

// ---------------- flash attention (round-13/14, passing) ----------------
// qk: [B*S][2048] bf16 (q|k per head); vt: [B][H][64][2048] bf16 (V transposed).
// Both lK and lVt staged directly via global_load_lds (pre-swizzled source chunk,
// linear dest). Swapped QK^T -> per-lane softmax raw-score domain; cvt_pk+permlane.
__global__ __launch_bounds__(256, 2) void attn_k(const unsigned short* __restrict__ qk,
                                                 const unsigned short* __restrict__ vt,
                                                 unsigned short* __restrict__ out) {
  __shared__ __align__(16) unsigned short lK[2][64 * 64];
  __shared__ __align__(16) unsigned short lVt[2][64 * 64];

  const int tid = threadIdx.x, wid = tid >> 6, lane = tid & 63;
  const int r = lane & 15, g = lane >> 4;
  const int bh = blockIdx.x;
  const int b = bh >> 4, h = bh & 15;
  const int qb = 15 - (int)blockIdx.y;   // long blocks dispatch first
  const int q0 = qb * 128;

  const unsigned short* Qg = qk + ((long)b * S_) * 2048 + h * 64;
  const unsigned short* Kg = Qg + 1024;
  const unsigned short* Vg = vt + ((long)(b * 16 + h)) * 64 * 2048;  // [e][s]

  // Q fragments for both subtiles
  int qrow[2];
  bf16x8 qf[2][2];
#pragma unroll
  for (int qs = 0; qs < 2; ++qs) {
    qrow[qs] = q0 + qs * 64 + wid * 16 + r;
#pragma unroll
    for (int kk = 0; kk < 2; ++kk)
      qf[qs][kk] = *(const bf16x8*)&Qg[(long)qrow[qs] * 2048 + kk * 32 + g * 8];
  }

  const f32x4 z4 = {0.f, 0.f, 0.f, 0.f};
  f32x4 o[2][4];
#pragma unroll
  for (int qs = 0; qs < 2; ++qs)
#pragma unroll
    for (int nt = 0; nt < 4; ++nt) o[qs][nt] = z4;
  float m_i[2] = {-1e30f, -1e30f};
  float l_i[2] = {0.f, 0.f};

  auto stage = [&](int buf, int t0) {
#pragma unroll
    for (int c = 0; c < 2; ++c) {
      const int j = c * 256 + tid;           // chunk id 0..511
      const int row = j >> 3, cc = j & 7;
      const int ccs = (cc ^ (row & 7)) << 3; // source element offset
      gload16(Kg + (long)(t0 + row) * 2048 + ccs, &lK[buf][j * 8]);
      gload16(Vg + (long)row * 2048 + t0 + ccs, &lVt[buf][j * 8]);
    }
  };

  const int ntiles = (q0 >> 6) + 2;  // kv tiles 0 .. q0/64+1
  stage(0, 0);

  for (int t = 0; t < ntiles; ++t) {
    const int cur = t & 1;
    __syncthreads();                              // drains vmcnt: lds[cur] ready;
                                                  // all waves done reading cur^1
    if (t + 1 < ntiles) stage(cur ^ 1, (t + 1) << 6);

    const int t0 = t << 6;
    const bool act0 = (t < ntiles - 1);   // qs=0 rows all < q0+64
    const bool diag0 = (t == ntiles - 2); // t0 == q0
    const bool diag1 = (t == ntiles - 1); // t0 == q0+64

    // S^T = K Q^T (swapped operands): st[qs][tt][rg] = S_raw[qrow[qs]][t0+16tt+4g+rg]
    f32x4 st[2][4];
#pragma unroll
    for (int tt = 0; tt < 4; ++tt) { st[0][tt] = z4; st[1][tt] = z4; }
    __builtin_amdgcn_s_setprio(1);
#pragma unroll
    for (int kk = 0; kk < 2; ++kk)
#pragma unroll
      for (int tt = 0; tt < 4; ++tt) {
        const int row = tt * 16 + r, cc = kk * 4 + g;
        bf16x8 kf = *(const bf16x8*)&lK[cur][(row * 8 + (cc ^ (row & 7))) * 8];
        st[1][tt] = __builtin_amdgcn_mfma_f32_16x16x32_bf16(kf, qf[1][kk], st[1][tt], 0, 0, 0);
        if (act0)
          st[0][tt] = __builtin_amdgcn_mfma_f32_16x16x32_bf16(kf, qf[0][kk], st[0][tt], 0, 0, 0);
      }
    __builtin_amdgcn_s_setprio(0);

    // per-lane softmax + in-register P repack, per active subtile
    bf16x8 pf[2][2];
    unsigned corr_bits[2] = {0x3f800000u, 0x3f800000u};
    bool dodef[2] = {true, true};
#pragma unroll
    for (int qs = 0; qs < 2; ++qs) {
      if (qs == 0 && !act0) continue;
      const bool diag = qs ? diag1 : diag0;
      float sv[16];
#pragma unroll
      for (int tt = 0; tt < 4; ++tt)
#pragma unroll
        for (int rg = 0; rg < 4; ++rg) {
          float s = st[qs][tt][rg];  // raw score (scale folded into exp)
          if (diag && (t0 + tt * 16 + g * 4 + rg > qrow[qs])) s = -1e30f;
          sv[tt * 4 + rg] = s;
        }
      float h0 = fmaxf(fmaxf(fmaxf(sv[0], sv[1]), fmaxf(sv[2], sv[3])),
                       fmaxf(fmaxf(sv[4], sv[5]), fmaxf(sv[6], sv[7])));
      float h1 = fmaxf(fmaxf(fmaxf(sv[8], sv[9]), fmaxf(sv[10], sv[11])),
                       fmaxf(fmaxf(sv[12], sv[13]), fmaxf(sv[14], sv[15])));
      const float pmax = fmaxf(h0, h1);
      const bool defer = __all(pmax - m_i[qs] <= 64.f);  // T13: 64 raw == 8 scaled
      float corr = 1.f;
      if (!defer) {
        float mx = fmaxf(pmax, m_i[qs]);
        mx = fmaxf(mx, __shfl_xor(mx, 16, 64));
        mx = fmaxf(mx, __shfl_xor(mx, 32, 64));
        corr = __expf((m_i[qs] - mx) * 0.125f);
        m_i[qs] = mx;
      }
      dodef[qs] = defer;
      corr_bits[qs] = __float_as_uint(corr);
      const float m8 = m_i[qs] * 0.125f;
      float p[16];
      float rs = 0.f;
#pragma unroll
      for (int i = 0; i < 16; ++i) {
        p[i] = __expf(__builtin_fmaf(sv[i], 0.125f, -m8));
        rs += p[i];
      }
      rs += __shfl_xor(rs, 16, 64);
      rs += __shfl_xor(rs, 32, 64);
      l_i[qs] = l_i[qs] * corr + rs;
      // pack pairs: c[tt][e] covers kv pair (16tt + 4g + 2e)
      unsigned cw[4][2];
#pragma unroll
      for (int tt = 0; tt < 4; ++tt)
#pragma unroll
        for (int e = 0; e < 2; ++e)
          asm("v_cvt_pk_bf16_f32 %0, %1, %2"
              : "=v"(cw[tt][e]) : "v"(p[tt * 4 + 2 * e]), "v"(p[tt * 4 + 2 * e + 1]));
      // redistribute to A-frag words
#pragma unroll
      for (int kk = 0; kk < 2; ++kk) {
        unsigned x0 = cw[2 * kk][0], y0 = cw[2 * kk + 1][0];
        unsigned x1 = cw[2 * kk][1], y1 = cw[2 * kk + 1][1];
        asm volatile("v_permlane32_swap_b32 %0, %1" : "+v"(x0), "+v"(y0));
        asm volatile("v_permlane16_swap_b32 %0, %1" : "+v"(x0), "+v"(y0));
        asm volatile("v_permlane32_swap_b32 %0, %1" : "+v"(x1), "+v"(y1));
        asm volatile("v_permlane16_swap_b32 %0, %1" : "+v"(x1), "+v"(y1));
        uint4v w = {x0, x1, y0, y1};  // kv pairs (8g+0),(8g+2),(8g+4),(8g+6)
        pf[qs][kk] = *(bf16x8*)&w;
      }
    }
    // O rescale (rows live at lanes r'=4g+rr; corr per-lane at r) — only when needed
#pragma unroll
    for (int qs = 0; qs < 2; ++qs) {
      if (qs == 0 && !act0) continue;
      if (!dodef[qs]) {
        const float corr = __uint_as_float(corr_bits[qs]);
#pragma unroll
        for (int rr = 0; rr < 4; ++rr) {
          const float c = __shfl(corr, g * 4 + rr, 64);
#pragma unroll
          for (int nt = 0; nt < 4; ++nt) o[qs][nt][rr] *= c;
        }
      }
    }

    // O += P V
    __builtin_amdgcn_s_setprio(1);
#pragma unroll
    for (int kk = 0; kk < 2; ++kk)
#pragma unroll
      for (int nt = 0; nt < 4; ++nt) {
        const int row = nt * 16 + r, cc = kk * 4 + g;
        const bf16x8 vf = *(const bf16x8*)&lVt[cur][(row * 8 + (cc ^ (row & 7))) * 8];
        o[1][nt] = __builtin_amdgcn_mfma_f32_16x16x32_bf16(pf[1][kk], vf, o[1][nt], 0, 0, 0);
        if (act0)
          o[0][nt] = __builtin_amdgcn_mfma_f32_16x16x32_bf16(pf[0][kk], vf, o[0][nt], 0, 0, 0);
      }
    __builtin_amdgcn_s_setprio(0);
  }

#pragma unroll
  for (int qs = 0; qs < 2; ++qs) {
    float linv[4];
#pragma unroll
    for (int rr = 0; rr < 4; ++rr)
      linv[rr] = 1.f / __shfl(l_i[qs], g * 4 + rr, 64);
#pragma unroll
    for (int nt = 0; nt < 4; ++nt)
#pragma unroll
      for (int rr = 0; rr < 4; ++rr) {
        const long s = q0 + qs * 64 + wid * 16 + g * 4 + rr;
        out[((long)b * S_ + s) * 1024 + h * 64 + nt * 16 + r] = f2bf(o[qs][nt][rr] * linv[rr]);
      }
  }
}

extern "C" void kernel_launch(void* const* d_in, const int* in_sizes, int n_in,
                              void* d_out, int out_size, void* d_ws, size_t ws_size,
                              hipStream_t stream) {
  const float* x = (const float*)d_in[0];
  const float* Wq = (const float*)d_in[1];
  const float* Wk = (const float*)d_in[2];
  const float* Wv = (const float*)d_in[3];
  const float* Wo = (const float*)d_in[4];
  const float* bo = (const float*)d_in[5];
  float* out = (float*)d_out;

  char* ws = (char*)d_ws;
  unsigned short* Xb = (unsigned short*)(ws);                        // 16 MiB: x bf16 [8192][1024]
  unsigned short* Wt = (unsigned short*)(ws + (16ul << 20));         //  6 MiB: qkv weight B^T [3072][1024]
  unsigned short* Wob = (unsigned short*)(ws + (22ul << 20));        //  2 MiB: Wo bf16 [1024][1024]
  unsigned short* QK = (unsigned short*)(ws + (24ul << 20));         // 32 MiB: [8192][2048]
  unsigned short* VT = (unsigned short*)(ws + (56ul << 20));         // 16 MiB: [B*H*64][2048]
  unsigned short* AO = (unsigned short*)(ws + (72ul << 20));         // 16 MiB: attn out [8192][1024]

  pack_x_k<<<2048, 256, 0, stream>>>(x, Xb, (B_ * S_ * D_) / 4);
  pack_x_k<<<512, 256, 0, stream>>>(Wo, Wob, (D_ * D_) / 4);
  pack_wqkv_k<<<(3 * D_ * D_) / 256, 256, 0, stream>>>(Wq, Wk, Wv, Wt);

  gemm256_k<<<dim3(32, 16), 512, 0, stream>>>(Xb, Wt, QK, VT, B_ * S_, 3 * D_, D_);
  attn_k<<<dim3(64, 16), 256, 0, stream>>>(QK, VT, AO);
  gemm_op_k<<<dim3(32, 8), 512, 0, stream>>>(AO, Wob, out, bo, B_ * S_, D_, D_);
}

// Round 16
// 178.027 us; speedup vs baseline: 1.0923x; 1.0042x over previous
//
#include <hip/hip_runtime.h>
#include <hip/hip_bf16.h>

typedef __bf16 bf16x8 __attribute__((ext_vector_type(8)));
typedef float f32x4 __attribute__((ext_vector_type(4)));
typedef unsigned short u16x4 __attribute__((ext_vector_type(4)));
typedef unsigned short u16x8 __attribute__((ext_vector_type(8)));
typedef unsigned uint4v __attribute__((ext_vector_type(4)));

#define B_ 4
#define S_ 2048
#define D_ 1024
#define H_ 16
#define HD_ 64

__device__ __forceinline__ unsigned short f2bf(float f) {
  unsigned u = __float_as_uint(f);
  u += 0x7fff + ((u >> 16) & 1);   // round-to-nearest-even
  return (unsigned short)(u >> 16);
}

__device__ __forceinline__ void gload16(const void* g, void* l) {
  __builtin_amdgcn_global_load_lds((const __attribute__((address_space(1))) unsigned int*)g,
                                   (__attribute__((address_space(3))) unsigned int*)l,
                                   16, 0, 0);
}

// ---------------- pack kernels ----------------
__global__ void pack_x_k(const float* __restrict__ in, unsigned short* __restrict__ out, int n4) {
  int i = blockIdx.x * blockDim.x + threadIdx.x;
  int stride = gridDim.x * blockDim.x;
  for (; i < n4; i += stride) {
    float4 v = reinterpret_cast<const float4*>(in)[i];
    u16x4 o = {f2bf(v.x), f2bf(v.y), f2bf(v.z), f2bf(v.w)};
    reinterpret_cast<u16x4*>(out)[i] = o;
  }
}

// Wq/Wk/Wv [H][D][HD] f32 -> Wt [3*D][D] bf16, Wt[h*64+e (+1024/2048)][d] = W[h][d][e]
__global__ void pack_wqkv_k(const float* __restrict__ Wq, const float* __restrict__ Wk,
                            const float* __restrict__ Wv, unsigned short* __restrict__ Wt) {
  int o = blockIdx.x * blockDim.x + threadIdx.x;  // 0 .. 3*1024*1024-1
  int n = o >> 10;
  int d = o & 1023;
  const float* W = (n < 1024) ? Wq : (n < 2048) ? Wk : Wv;
  int nn = n & 1023;
  int h = nn >> 6, e = nn & 63;
  Wt[o] = f2bf(W[(h << 16) + (d << 6) + e]);
}

// ---------------- 256x192 2-phase GEMM (QKV proj) ----------------
// (byte-identical to round 15, passing)
__global__ __launch_bounds__(512, 2) void gemm256_k(const unsigned short* __restrict__ A,
                                                    const unsigned short* __restrict__ Bt,
                                                    unsigned short* __restrict__ QK,
                                                    unsigned short* __restrict__ VT,
                                                    int M, int N, int K) {
  __shared__ __align__(16) unsigned short lA0[2][128 * 64];
  __shared__ __align__(16) unsigned short lA1[2][128 * 64];
  __shared__ __align__(16) unsigned short lB[2][192 * 64];
  const int tid = threadIdx.x;
  const int wid = tid >> 6, lane = tid & 63;
  const int r = lane & 15, g = lane >> 4;
  const int wm = wid >> 2, wn = wid & 3;

  const int i_hw = blockIdx.y * gridDim.x + blockIdx.x;
  const int xcd = i_hw & 7, j = i_hw >> 3;          // j in 0..63
  const long arow0 = (long)((xcd & 3) * 8 + (j & 7)) * 256;
  const long bcol0 = (long)((xcd >> 2) * 8 + (j >> 3)) * 192;

  const f32x4 z4 = {0.f, 0.f, 0.f, 0.f};
  f32x4 acc[8][3];
#pragma unroll
  for (int m = 0; m < 8; ++m)
#pragma unroll
    for (int n = 0; n < 3; ++n) acc[m][n] = z4;

  auto stage_half = [&](int kt, int which) {
    const unsigned short* src = (which == 2) ? Bt + bcol0 * K : A + (arow0 + 128 * which) * K;
    const int k0 = kt << 6;
    unsigned short* base = (which == 0) ? &lA0[kt & 1][0]
                         : (which == 1) ? &lA1[kt & 1][0] : &lB[kt & 1][0];
    const int nch = (which == 2) ? 3 : 2;
    for (int c = 0; c < nch; ++c) {
      const int jj = c * 512 + tid;
      const int row = jj >> 3, cc = jj & 7;
      const int ccs = cc ^ (row & 7);
      gload16(src + (long)row * K + k0 + ccs * 8, base + jj * 8);
    }
  };

  bf16x8 af[4][2], bv[3][2];
  auto read_a = [&](const unsigned short* lbase) {
#pragma unroll
    for (int i2 = 0; i2 < 4; ++i2)
#pragma unroll
      for (int kk = 0; kk < 2; ++kk) {
        const int rowh = (2 * i2 + wm) * 16 + r;
        af[i2][kk] = *(const bf16x8*)&lbase[rowh * 64 + (((kk << 2) + g) ^ (rowh & 7)) * 8];
      }
  };
  auto read_b = [&](int buf) {
#pragma unroll
    for (int j2 = 0; j2 < 3; ++j2)
#pragma unroll
      for (int kk = 0; kk < 2; ++kk) {
        const int rowh = (4 * j2 + wn) * 16 + r;
        bv[j2][kk] = *(const bf16x8*)&lB[buf][rowh * 64 + (((kk << 2) + g) ^ (rowh & 7)) * 8];
      }
  };
  auto mma_h = [&](int mh) {
    __builtin_amdgcn_s_setprio(1);
#pragma unroll
    for (int kk = 0; kk < 2; ++kk)
#pragma unroll
      for (int i2 = 0; i2 < 4; ++i2)
#pragma unroll
        for (int j2 = 0; j2 < 3; ++j2)
          acc[4 * mh + i2][j2] = __builtin_amdgcn_mfma_f32_16x16x32_bf16(
              af[i2][kk], bv[j2][kk], acc[4 * mh + i2][j2], 0, 0, 0);
    __builtin_amdgcn_s_setprio(0);
  };

  const int nk = K >> 6;
  stage_half(0, 0);
  stage_half(0, 2);
  stage_half(0, 1);
  asm volatile("s_waitcnt vmcnt(2)" ::: "memory");
  asm volatile("s_barrier" ::: "memory");

  for (int t = 0; t < nk; ++t) {
    const int buf = t & 1;
    const bool pre = (t + 1 < nk);
    read_a(&lA0[buf][0]);
    read_b(buf);
    if (pre) { stage_half(t + 1, 0); stage_half(t + 1, 2); }
    asm volatile("s_barrier" ::: "memory");
    mma_h(0);
    if (pre) asm volatile("s_waitcnt vmcnt(5)" ::: "memory");
    else     asm volatile("s_waitcnt vmcnt(0)" ::: "memory");
    asm volatile("s_waitcnt lgkmcnt(0)\n\ts_barrier" ::: "memory");
    read_a(&lA1[buf][0]);
    if (pre) stage_half(t + 1, 1);
    asm volatile("s_barrier" ::: "memory");
    mma_h(1);
    if (pre) asm volatile("s_waitcnt vmcnt(2)" ::: "memory");
    asm volatile("s_waitcnt lgkmcnt(0)\n\ts_barrier" ::: "memory");
  }

#pragma unroll
  for (int j2 = 0; j2 < 3; ++j2) {
    const long colb = bcol0 + (4 * j2 + wn) * 16;
    if (colb < 2048) {
#pragma unroll
      for (int m = 0; m < 8; ++m)
#pragma unroll
        for (int rr = 0; rr < 4; ++rr) {
          const long row = arow0 + (2 * m + wm) * 16 + g * 4 + rr;
          QK[row * 2048 + colb + r] = f2bf(acc[m][j2][rr]);
        }
    } else {
      const long vcol = colb - 2048 + r;
      const long h = vcol >> 6, e = vcol & 63;
#pragma unroll
      for (int m = 0; m < 8; ++m) {
        const long row0 = arow0 + (2 * m + wm) * 16 + g * 4;
        const long b = row0 >> 11, s = row0 & 2047;
        u16x4 w4;
#pragma unroll
        for (int rr = 0; rr < 4; ++rr) w4[rr] = f2bf(acc[m][j2][rr]);
        *(u16x4*)&VT[(((b << 4) + h) * 64 + e) * 2048 + s] = w4;
      }
    }
  }
}

// ---------------- 256x128 2-phase GEMM (out-proj) ----------------
// (byte-identical to round 15, passing)
__global__ __launch_bounds__(512, 2) void gemm_op_k(const unsigned short* __restrict__ A,
                                                    const unsigned short* __restrict__ Bt,
                                                    float* __restrict__ C,
                                                    const float* __restrict__ bias,
                                                    int M, int N, int K) {
  __shared__ __align__(16) unsigned short lA0[2][128 * 64];
  __shared__ __align__(16) unsigned short lA1[2][128 * 64];
  __shared__ __align__(16) unsigned short lB[2][128 * 64];
  const int tid = threadIdx.x;
  const int wid = tid >> 6, lane = tid & 63;
  const int r = lane & 15, g = lane >> 4;
  const int wm = wid >> 2, wn = wid & 3;

  const int i_hw = blockIdx.y * gridDim.x + blockIdx.x;
  const int xcd = i_hw & 7, j = i_hw >> 3;
  const long arow0 = (long)((xcd & 3) * 8 + (j & 7)) * 256;
  const long bcol0 = (long)((xcd >> 2) * 4 + (j >> 3)) * 128;

  const f32x4 z4 = {0.f, 0.f, 0.f, 0.f};
  f32x4 acc[8][2];
#pragma unroll
  for (int m = 0; m < 8; ++m)
#pragma unroll
    for (int n = 0; n < 2; ++n) acc[m][n] = z4;

  auto stage_half = [&](int kt, int which) {
    const unsigned short* src = (which == 2) ? Bt + bcol0 * K : A + (arow0 + 128 * which) * K;
    const int k0 = kt << 6;
    unsigned short* base = (which == 0) ? &lA0[kt & 1][0]
                         : (which == 1) ? &lA1[kt & 1][0] : &lB[kt & 1][0];
#pragma unroll
    for (int c = 0; c < 2; ++c) {
      const int jj = c * 512 + tid;
      const int row = jj >> 3, cc = jj & 7;
      const int ccs = cc ^ (row & 7);
      gload16(src + (long)row * K + k0 + ccs * 8, base + jj * 8);
    }
  };

  bf16x8 af[4][2], bv[2][2];
  auto read_a = [&](const unsigned short* lbase) {
#pragma unroll
    for (int i2 = 0; i2 < 4; ++i2)
#pragma unroll
      for (int kk = 0; kk < 2; ++kk) {
        const int rowh = (2 * i2 + wm) * 16 + r;
        af[i2][kk] = *(const bf16x8*)&lbase[rowh * 64 + (((kk << 2) + g) ^ (rowh & 7)) * 8];
      }
  };
  auto read_b = [&](int buf) {
#pragma unroll
    for (int j2 = 0; j2 < 2; ++j2)
#pragma unroll
      for (int kk = 0; kk < 2; ++kk) {
        const int rowh = (4 * j2 + wn) * 16 + r;
        bv[j2][kk] = *(const bf16x8*)&lB[buf][rowh * 64 + (((kk << 2) + g) ^ (rowh & 7)) * 8];
      }
  };
  auto mma_h = [&](int mh) {
    __builtin_amdgcn_s_setprio(1);
#pragma unroll
    for (int kk = 0; kk < 2; ++kk)
#pragma unroll
      for (int i2 = 0; i2 < 4; ++i2)
#pragma unroll
        for (int j2 = 0; j2 < 2; ++j2)
          acc[4 * mh + i2][j2] = __builtin_amdgcn_mfma_f32_16x16x32_bf16(
              af[i2][kk], bv[j2][kk], acc[4 * mh + i2][j2], 0, 0, 0);
    __builtin_amdgcn_s_setprio(0);
  };

  const int nk = K >> 6;
  stage_half(0, 0);
  stage_half(0, 2);
  stage_half(0, 1);
  asm volatile("s_waitcnt vmcnt(2)" ::: "memory");
  asm volatile("s_barrier" ::: "memory");

  for (int t = 0; t < nk; ++t) {
    const int buf = t & 1;
    const bool pre = (t + 1 < nk);
    read_a(&lA0[buf][0]);
    read_b(buf);
    if (pre) { stage_half(t + 1, 0); stage_half(t + 1, 2); }
    asm volatile("s_barrier" ::: "memory");
    mma_h(0);
    if (pre) asm volatile("s_waitcnt vmcnt(4)" ::: "memory");
    else     asm volatile("s_waitcnt vmcnt(0)" ::: "memory");
    asm volatile("s_waitcnt lgkmcnt(0)\n\ts_barrier" ::: "memory");
    read_a(&lA1[buf][0]);
    if (pre) stage_half(t + 1, 1);
    asm volatile("s_barrier" ::: "memory");
    mma_h(1);
    if (pre) asm volatile("s_waitcnt vmcnt(2)" ::: "memory");
    asm volatile("s_waitcnt lgkmcnt(0)\n\ts_barrier" ::: "memory");
  }

#pragma unroll
  for (int m = 0; m < 8; ++m)
#pragma unroll
    for (int n = 0; n < 2; ++n)
#pragma unroll
      for (int rr = 0; rr < 4; ++rr) {
        const long row = arow0 + (2 * m + wm) * 16 + g * 4 + rr;
        const long col = bcol0 + (4 * n + wn) * 16 + r;
        C[row * N + col] = acc[m][n][rr] + bias[col];
      }
}

// ---------------- flash attention (r15 + wave-uniform diag branch) ----------------
// qk: [B*S][2048] bf16 (q|k per head); vt: [B][H][64][2048] bf16 (V transposed).
// Changes vs r15 (passing): (1) causal mask built only on diagonal tiles via a
// wave-uniform branch (removes 32 v_cmp + 32 v_cndmask per non-diag tile);
// (2) staging base pointers incremented per tile (no per-gload address MADs).
__global__ __launch_bounds__(256, 2) void attn_k(const unsigned short* __restrict__ qk,
                                                 const unsigned short* __restrict__ vt,
                                                 unsigned short* __restrict__ out) {
  __shared__ __align__(16) unsigned short lK[2][64 * 64];
  __shared__ __align__(16) unsigned short lVt[2][64 * 64];

  const int tid = threadIdx.x, wid = tid >> 6, lane = tid & 63;
  const int r = lane & 15, g = lane >> 4;
  const int bh = blockIdx.x;
  const int b = bh >> 4, h = bh & 15;
  const int qb = 15 - (int)blockIdx.y;   // long blocks dispatch first
  const int q0 = qb * 128;

  const unsigned short* Qg = qk + ((long)b * S_) * 2048 + h * 64;
  const unsigned short* Kg = Qg + 1024;
  const unsigned short* Vg = vt + ((long)(b * 16 + h)) * 64 * 2048;  // [e][s]

  // Q fragments for both subtiles
  int qrow[2];
  bf16x8 qf[2][2];
#pragma unroll
  for (int qs = 0; qs < 2; ++qs) {
    qrow[qs] = q0 + qs * 64 + wid * 16 + r;
#pragma unroll
    for (int kk = 0; kk < 2; ++kk)
      qf[qs][kk] = *(const bf16x8*)&Qg[(long)qrow[qs] * 2048 + kk * 32 + g * 8];
  }

  const f32x4 z4 = {0.f, 0.f, 0.f, 0.f};
  f32x4 o[2][4];
#pragma unroll
  for (int qs = 0; qs < 2; ++qs)
#pragma unroll
    for (int nt = 0; nt < 4; ++nt) o[qs][nt] = z4;
  float m_i[2] = {-1e30f, -1e30f};
  float l_i[2] = {0.f, 0.f};

  // staging: per-lane fixed offsets; bases advance per tile (no per-gload MADs)
  const int srow = tid >> 3, scc = tid & 7;
  const int sccs = (scc ^ (srow & 7)) << 3;
  const unsigned short* kp = Kg + (long)srow * 2048 + sccs;       // + t0*2048 per tile
  const unsigned short* kp2 = Kg + (long)(srow + 32) * 2048 + sccs;
  const unsigned short* vp = Vg + (long)srow * 2048 + sccs;       // + t0 per tile
  const unsigned short* vp2 = Vg + (long)(srow + 32) * 2048 + sccs;
  auto stage = [&](int buf, long koff, long voff) {
    gload16(kp + koff, &lK[buf][tid * 8]);
    gload16(kp2 + koff, &lK[buf][(256 + tid) * 8]);
    gload16(vp + voff, &lVt[buf][tid * 8]);
    gload16(vp2 + voff, &lVt[buf][(256 + tid) * 8]);
  };

  const int ntiles = (q0 >> 6) + 2;  // kv tiles 0 .. q0/64+1
  stage(0, 0, 0);

  for (int t = 0; t < ntiles; ++t) {
    const int cur = t & 1;
    __syncthreads();                              // drains vmcnt: lds[cur] ready;
                                                  // all waves done reading cur^1
    if (t + 1 < ntiles) stage(cur ^ 1, (long)(t + 1) * 64 * 2048, (long)(t + 1) * 64);

    const int t0 = t << 6;
    const bool act0 = (t < ntiles - 1);   // qs=0 rows all < q0+64
    const bool diag0 = (t == ntiles - 2); // t0 == q0
    const bool diag1 = (t == ntiles - 1); // t0 == q0+64

    // S^T = K Q^T (swapped operands): st[qs][tt][rg] = S_raw[qrow[qs]][t0+16tt+4g+rg]
    f32x4 st[2][4];
#pragma unroll
    for (int tt = 0; tt < 4; ++tt) { st[0][tt] = z4; st[1][tt] = z4; }
    __builtin_amdgcn_s_setprio(1);
#pragma unroll
    for (int kk = 0; kk < 2; ++kk)
#pragma unroll
      for (int tt = 0; tt < 4; ++tt) {
        const int row = tt * 16 + r, cc = kk * 4 + g;
        bf16x8 kf = *(const bf16x8*)&lK[cur][(row * 8 + (cc ^ (row & 7))) * 8];
        st[1][tt] = __builtin_amdgcn_mfma_f32_16x16x32_bf16(kf, qf[1][kk], st[1][tt], 0, 0, 0);
        if (act0)
          st[0][tt] = __builtin_amdgcn_mfma_f32_16x16x32_bf16(kf, qf[0][kk], st[0][tt], 0, 0, 0);
      }
    __builtin_amdgcn_s_setprio(0);

    // per-lane softmax + in-register P repack, per active subtile
    bf16x8 pf[2][2];
    unsigned corr_bits[2] = {0x3f800000u, 0x3f800000u};
    bool dodef[2] = {true, true};
#pragma unroll
    for (int qs = 0; qs < 2; ++qs) {
      if (qs == 0 && !act0) continue;
      const bool diag = qs ? diag1 : diag0;
      float sv[16];
      if (diag) {  // wave-uniform branch: mask built only on diagonal tiles
#pragma unroll
        for (int tt = 0; tt < 4; ++tt)
#pragma unroll
          for (int rg = 0; rg < 4; ++rg) {
            float s = st[qs][tt][rg];
            if (t0 + tt * 16 + g * 4 + rg > qrow[qs]) s = -1e30f;
            sv[tt * 4 + rg] = s;
          }
      } else {
#pragma unroll
        for (int tt = 0; tt < 4; ++tt)
#pragma unroll
          for (int rg = 0; rg < 4; ++rg) sv[tt * 4 + rg] = st[qs][tt][rg];
      }
      float h0 = fmaxf(fmaxf(fmaxf(sv[0], sv[1]), fmaxf(sv[2], sv[3])),
                       fmaxf(fmaxf(sv[4], sv[5]), fmaxf(sv[6], sv[7])));
      float h1 = fmaxf(fmaxf(fmaxf(sv[8], sv[9]), fmaxf(sv[10], sv[11])),
                       fmaxf(fmaxf(sv[12], sv[13]), fmaxf(sv[14], sv[15])));
      const float pmax = fmaxf(h0, h1);
      const bool defer = __all(pmax - m_i[qs] <= 64.f);  // T13: 64 raw == 8 scaled
      float corr = 1.f;
      if (!defer) {
        float mx = fmaxf(pmax, m_i[qs]);
        mx = fmaxf(mx, __shfl_xor(mx, 16, 64));
        mx = fmaxf(mx, __shfl_xor(mx, 32, 64));
        corr = __expf((m_i[qs] - mx) * 0.125f);
        m_i[qs] = mx;
      }
      dodef[qs] = defer;
      corr_bits[qs] = __float_as_uint(corr);
      const float m8 = m_i[qs] * 0.125f;
      float p[16];
      float rs = 0.f;
#pragma unroll
      for (int i = 0; i < 16; ++i) {
        p[i] = __expf(__builtin_fmaf(sv[i], 0.125f, -m8));
        rs += p[i];
      }
      rs += __shfl_xor(rs, 16, 64);
      rs += __shfl_xor(rs, 32, 64);
      l_i[qs] = l_i[qs] * corr + rs;
      // pack pairs: c[tt][e] covers kv pair (16tt + 4g + 2e)
      unsigned cw[4][2];
#pragma unroll
      for (int tt = 0; tt < 4; ++tt)
#pragma unroll
        for (int e = 0; e < 2; ++e)
          asm("v_cvt_pk_bf16_f32 %0, %1, %2"
              : "=v"(cw[tt][e]) : "v"(p[tt * 4 + 2 * e]), "v"(p[tt * 4 + 2 * e + 1]));
      // redistribute to A-frag words
#pragma unroll
      for (int kk = 0; kk < 2; ++kk) {
        unsigned x0 = cw[2 * kk][0], y0 = cw[2 * kk + 1][0];
        unsigned x1 = cw[2 * kk][1], y1 = cw[2 * kk + 1][1];
        asm volatile("v_permlane32_swap_b32 %0, %1" : "+v"(x0), "+v"(y0));
        asm volatile("v_permlane16_swap_b32 %0, %1" : "+v"(x0), "+v"(y0));
        asm volatile("v_permlane32_swap_b32 %0, %1" : "+v"(x1), "+v"(y1));
        asm volatile("v_permlane16_swap_b32 %0, %1" : "+v"(x1), "+v"(y1));
        uint4v w = {x0, x1, y0, y1};  // kv pairs (8g+0),(8g+2),(8g+4),(8g+6)
        pf[qs][kk] = *(bf16x8*)&w;
      }
    }
    // O rescale (rows live at lanes r'=4g+rr; corr per-lane at r) — only when needed
#pragma unroll
    for (int qs = 0; qs < 2; ++qs) {
      if (qs == 0 && !act0) continue;
      if (!dodef[qs]) {
        const float corr = __uint_as_float(corr_bits[qs]);
#pragma unroll
        for (int rr = 0; rr < 4; ++rr) {
          const float c = __shfl(corr, g * 4 + rr, 64);
#pragma unroll
          for (int nt = 0; nt < 4; ++nt) o[qs][nt][rr] *= c;
        }
      }
    }

    // O += P V
    __builtin_amdgcn_s_setprio(1);
#pragma unroll
    for (int kk = 0; kk < 2; ++kk)
#pragma unroll
      for (int nt = 0; nt < 4; ++nt) {
        const int row = nt * 16 + r, cc = kk * 4 + g;
        const bf16x8 vf = *(const bf16x8*)&lVt[cur][(row * 8 + (cc ^ (row & 7))) * 8];
        o[1][nt] = __builtin_amdgcn_mfma_f32_16x16x32_bf16(pf[1][kk], vf, o[1][nt], 0, 0, 0);
        if (act0)
          o[0][nt] = __builtin_amdgcn_mfma_f32_16x16x32_bf16(pf[0][kk], vf, o[0][nt], 0, 0, 0);
      }
    __builtin_amdgcn_s_setprio(0);
  }

#pragma unroll
  for (int qs = 0; qs < 2; ++qs) {
    float linv[4];
#pragma unroll
    for (int rr = 0; rr < 4; ++rr)
      linv[rr] = 1.f / __shfl(l_i[qs], g * 4 + rr, 64);
#pragma unroll
    for (int nt = 0; nt < 4; ++nt)
#pragma unroll
      for (int rr = 0; rr < 4; ++rr) {
        const long s = q0 + qs * 64 + wid * 16 + g * 4 + rr;
        out[((long)b * S_ + s) * 1024 + h * 64 + nt * 16 + r] = f2bf(o[qs][nt][rr] * linv[rr]);
      }
  }
}

extern "C" void kernel_launch(void* const* d_in, const int* in_sizes, int n_in,
                              void* d_out, int out_size, void* d_ws, size_t ws_size,
                              hipStream_t stream) {
  const float* x = (const float*)d_in[0];
  const float* Wq = (const float*)d_in[1];
  const float* Wk = (const float*)d_in[2];
  const float* Wv = (const float*)d_in[3];
  const float* Wo = (const float*)d_in[4];
  const float* bo = (const float*)d_in[5];
  float* out = (float*)d_out;

  char* ws = (char*)d_ws;
  unsigned short* Xb = (unsigned short*)(ws);                        // 16 MiB: x bf16 [8192][1024]
  unsigned short* Wt = (unsigned short*)(ws + (16ul << 20));         //  6 MiB: qkv weight B^T [3072][1024]
  unsigned short* Wob = (unsigned short*)(ws + (22ul << 20));        //  2 MiB: Wo bf16 [1024][1024]
  unsigned short* QK = (unsigned short*)(ws + (24ul << 20));         // 32 MiB: [8192][2048]
  unsigned short* VT = (unsigned short*)(ws + (56ul << 20));         // 16 MiB: [B*H*64][2048]
  unsigned short* AO = (unsigned short*)(ws + (72ul << 20));         // 16 MiB: attn out [8192][1024]

  pack_x_k<<<2048, 256, 0, stream>>>(x, Xb, (B_ * S_ * D_) / 4);
  pack_x_k<<<512, 256, 0, stream>>>(Wo, Wob, (D_ * D_) / 4);
  pack_wqkv_k<<<(3 * D_ * D_) / 256, 256, 0, stream>>>(Wq, Wk, Wv, Wt);

  gemm256_k<<<dim3(32, 16), 512, 0, stream>>>(Xb, Wt, QK, VT, B_ * S_, 3 * D_, D_);
  attn_k<<<dim3(64, 16), 256, 0, stream>>>(QK, VT, AO);
  gemm_op_k<<<dim3(32, 8), 512, 0, stream>>>(AO, Wob, out, bo, B_ * S_, D_, D_);
}